// Round 3
// baseline (233.459 us; speedup 1.0000x reference)
//
#include <hip/hip_runtime.h>
#include <hip/hip_bf16.h>
#include <cstdint>
#include <cstddef>

using bf16 = __hip_bfloat16;
using short8 = __attribute__((ext_vector_type(8))) short;
using f32x4  = __attribute__((ext_vector_type(4))) float;
using f32x16 = __attribute__((ext_vector_type(16))) float;

#define DEVI __device__ __forceinline__

// async global->LDS, 16B per lane. LDS dest is wave-uniform base + lane*16.
DEVI void async_ld16(const void* g, void* l) {
  __builtin_amdgcn_global_load_lds(
      (const __attribute__((address_space(1))) unsigned int*)g,
      (__attribute__((address_space(3))) unsigned int*)l, 16, 0, 0);
}

DEVI unsigned int cvt_pk_bf16(float lo, float hi) {
  unsigned int r;
  asm("v_cvt_pk_bf16_f32 %0, %1, %2" : "=v"(r) : "v"(lo), "v"(hi));
  return r;
}

// ---------------------------------------------------------------- cvt f32->bf16
__global__ void cvt_f32_bf16(const float* __restrict__ in, bf16* __restrict__ out, int n4) {
  int i = blockIdx.x * blockDim.x + threadIdx.x;
  if (i >= n4) return;
  float4 v = ((const float4*)in)[i];
  union { bf16 h[4]; ushort4 u; } o;
  o.h[0] = __float2bfloat16(v.x);
  o.h[1] = __float2bfloat16(v.y);
  o.h[2] = __float2bfloat16(v.z);
  o.h[3] = __float2bfloat16(v.w);
  ((ushort4*)out)[i] = o.u;
}

// ------------------------------------------- transpose + cvt: in[K][N] -> out[N][K]
__global__ __launch_bounds__(256) void transpose_cvt(
    const float* __restrict__ in, bf16* __restrict__ out, int K, int N) {
  __shared__ float tile[32][33];
  int n0 = blockIdx.x * 32, k0 = blockIdx.y * 32;
  int tx = threadIdx.x & 31, ty = threadIdx.x >> 5;  // 32 x 8
#pragma unroll
  for (int i = 0; i < 32; i += 8)
    tile[ty + i][tx] = in[(size_t)(k0 + ty + i) * N + n0 + tx];
  __syncthreads();
#pragma unroll
  for (int i = 0; i < 32; i += 8)
    out[(size_t)(n0 + ty + i) * K + k0 + tx] = __float2bfloat16(tile[tx][ty + i]);
}

// ----------------------- V transpose: Vt[b*8+kvh][hd][t] <- qkv[b*2048+t][3072+kvh*128+hd]
__global__ __launch_bounds__(256) void v_transpose(
    const bf16* __restrict__ qkv, bf16* __restrict__ Vt) {
  __shared__ bf16 tile[32][34];
  int bk = blockIdx.z;                       // 0..15
  int t0 = blockIdx.x * 32, h0 = blockIdx.y * 32;
  int tx = threadIdx.x & 31, ty = threadIdx.x >> 5;  // 32 x 8
  int b = bk >> 3, kvh = bk & 7;
  const bf16* src = qkv + (size_t)(b * 2048) * 4096 + 3072 + kvh * 128;
#pragma unroll
  for (int i = 0; i < 32; i += 8)
    tile[ty + i][tx] = src[(size_t)(t0 + ty + i) * 4096 + h0 + tx];
  __syncthreads();
  bf16* dst = Vt + (size_t)bk * 128 * 2048;
#pragma unroll
  for (int i = 0; i < 32; i += 8)
    dst[(size_t)(h0 + ty + i) * 2048 + t0 + tx] = tile[tx][ty + i];
}

// ---------------------------------------------------------------- rope table
__global__ void rope_tab(float2* __restrict__ tab) {
  int t = blockIdx.x, i = threadIdx.x;  // T blocks x 64 threads
  float ex = -2.f * (float)i * (1.f / 128.f);
  float theta = exp2f(ex * 19.9315685693241741f);  // log2(1e6)
  float f = (float)t * theta;
  float sv, cv;
  sincosf(f, &sv, &cv);
  tab[t * 64 + i] = make_float2(cv, sv);
}

// ------------------------------------------------- GEMM: C[M][N] = A[M][K] * Bt[N][K]^T
template <bool OUT_F32>
__global__ __launch_bounds__(256) void gemm_bt(
    const bf16* __restrict__ A, const bf16* __restrict__ Bt,
    void* __restrict__ Cv, int M, int N, int K) {
  __shared__ alignas(16) bf16 As[128 * 64];
  __shared__ alignas(16) bf16 Bs[128 * 64];
  const int tid = threadIdx.x, lane = tid & 63, w = tid >> 6;
  const int wm = w >> 1, wn = w & 1;
  const int m0 = blockIdx.y * 128, n0 = blockIdx.x * 128;
  f32x4 acc[4][4] = {};

  const int srow = lane >> 3;          // row within 8-row slab
  const int scb  = (lane & 7) * 16;    // linear col byte

  for (int kt = 0; kt < K; kt += 64) {
#pragma unroll
    for (int i = 0; i < 4; i++) {
      int row = w * 32 + i * 8 + srow;
      int src_cb = scb ^ ((row & 7) << 4);
      async_ld16((const char*)(A  + (size_t)(m0 + row) * K + kt) + src_cb,
                 (char*)As + w * 4096 + i * 1024);
      async_ld16((const char*)(Bt + (size_t)(n0 + row) * K + kt) + src_cb,
                 (char*)Bs + w * 4096 + i * 1024);
    }
    __syncthreads();
#pragma unroll
    for (int ks = 0; ks < 2; ks++) {
      short8 af[4], bfr[4];
#pragma unroll
      for (int mi = 0; mi < 4; mi++) {
        int row = wm * 64 + mi * 16 + (lane & 15);
        int cb = (ks * 64 + (lane >> 4) * 16) ^ ((row & 7) << 4);
        af[mi] = *(const short8*)((const char*)As + row * 128 + cb);
      }
#pragma unroll
      for (int ni = 0; ni < 4; ni++) {
        int row = wn * 64 + ni * 16 + (lane & 15);
        int cb = (ks * 64 + (lane >> 4) * 16) ^ ((row & 7) << 4);
        bfr[ni] = *(const short8*)((const char*)Bs + row * 128 + cb);
      }
#pragma unroll
      for (int mi = 0; mi < 4; mi++)
#pragma unroll
        for (int ni = 0; ni < 4; ni++)
          acc[mi][ni] = __builtin_amdgcn_mfma_f32_16x16x32_bf16(af[mi], bfr[ni], acc[mi][ni], 0, 0, 0);
    }
    __syncthreads();
  }

  const int c0 = n0 + wn * 64 + (lane & 15);
  const int r0 = m0 + wm * 64 + (lane >> 4) * 4;
#pragma unroll
  for (int mi = 0; mi < 4; mi++)
#pragma unroll
    for (int ni = 0; ni < 4; ni++)
#pragma unroll
      for (int r = 0; r < 4; r++) {
        size_t idx = (size_t)(r0 + mi * 16 + r) * N + (c0 + ni * 16);
        float v = acc[mi][ni][r];
        if constexpr (OUT_F32) ((float*)Cv)[idx] = v;
        else                   ((bf16*)Cv)[idx] = __float2bfloat16(v);
      }
}

// ------------------------- RMSNorm + RoPE + relayout to [B][H][T][HD] bf16 (Q,K only)
__global__ __launch_bounds__(256) void norm_rope(
    const bf16* __restrict__ qkv, const float* __restrict__ qw, const float* __restrict__ kw,
    const float2* __restrict__ tab,
    bf16* __restrict__ Qh, bf16* __restrict__ Kh) {
  const int lane = threadIdx.x & 63;
  const int slot = blockIdx.x * 4 + (threadIdx.x >> 6);  // 0..23
  const int m = blockIdx.y;
  const int b = m >> 11, t = m & 2047;

  int type = slot < 16 ? 0 : 1;
  int h = type ? slot - 16 : slot;
  int col = type ? 2048 + h * 128 : h * 128;

  const bf16* src = qkv + (size_t)m * 4096 + col + lane * 2;
  bf16* dst = type
      ? Kh + ((size_t)(b * 8 + h) * 2048 + t) * 128 + lane * 2
      : Qh + ((size_t)(b * 16 + h) * 2048 + t) * 128 + lane * 2;

  float x0 = __bfloat162float(src[0]);
  float x1 = __bfloat162float(src[1]);

  float ss = x0 * x0 + x1 * x1;
#pragma unroll
  for (int o = 1; o < 64; o <<= 1) ss += __shfl_xor(ss, o);
  float rms = sqrtf(ss * (1.f / 128.f));
  float inv = 1.f / (rms + 1e-6f);
  const float* wn = type ? kw : qw;
  float n0 = wn[lane * 2] * x0 * inv;
  float n1 = wn[lane * 2 + 1] * x1 * inv;
  float2 cs = tab[t * 64 + lane];
  dst[0] = __float2bfloat16(n0 * cs.x - n1 * cs.y);
  dst[1] = __float2bfloat16(n0 * cs.y + n1 * cs.x);
}

// ---------------------------------------------------- flash attention v3 (8-warp 32x32)
// 512 thr (8 warps x 32 q-rows = 256-q tile), KVBLK=64, swapped QK^T (S^T = K.Q^T),
// in-register softmax (lane owns one q row), P->A-frag via cvt_pk + shfl_xor(32),
// defer-max (THR=8, log2 domain), K/V double-buffered via global_load_lds.
__global__ __launch_bounds__(512, 2) void flash_attn3(
    const bf16* __restrict__ Qh, const bf16* __restrict__ Kh,
    const bf16* __restrict__ Vt, bf16* __restrict__ Y) {
  __shared__ alignas(16) bf16 Ks[2][64 * 128];   // [key][hd] rows 256B, XOR-swizzled
  __shared__ alignas(16) bf16 Vs[2][128 * 64];   // [hd][key] rows 128B, XOR-swizzled
  const int tid = threadIdx.x, lane = tid & 63, w = tid >> 6;
  const int hi = lane >> 5, lq = lane & 31;

  // grid 256 = 8 qt x 32 bh; XCD x owns bh {4x..4x+3} (K/V stays in XCD-local L2)
  const int g = blockIdx.x;
  const int bh = (g & 7) * 4 + (g >> 6);
  const int qt = (g >> 3) & 7;
  const int b = bh >> 4, h = bh & 15, kvh = h >> 1;

  const int q0 = qt * 256, nk = 4 * qt + 4, qw = q0 + w * 32;
  const int qg = qw + lq;  // this lane's q row (softmax owner)

  const bf16* Qg = Qh + (size_t)(b * 16 + h) * 2048 * 128;
  const bf16* Kg = Kh + (size_t)(b * 8 + kvh) * 2048 * 128;
  const bf16* Vg = Vt + (size_t)(b * 8 + kvh) * 128 * 2048;

  // Q fragments: B-operand of 32x32x16 (col=lane&31=q, k(d)=hi*8+j)
  short8 qf[8];
#pragma unroll
  for (int dc = 0; dc < 8; dc++)
    qf[dc] = *(const short8*)(Qg + (size_t)qg * 128 + dc * 16 + hi * 8);

  f32x16 oacc[4] = {};   // O[32q][128d]: col=lane&31=d, row=q=(r&3)+8*(r>>2)+4*hi
  float m = -1e30f, l = 0.f;

  auto stage = [&](int buf, int k0) {
#pragma unroll
    for (int i = 0; i < 2; i++) {
      int c = w * 2 + i;
      {  // K chunk: 4 rows x 256B
        int row = c * 4 + (lane >> 4);
        int cb = ((lane & 15) * 16) ^ ((row & 7) << 4);
        async_ld16((const char*)Kg + (size_t)(k0 + row) * 256 + cb,
                   (char*)Ks[buf] + c * 1024);
      }
      {  // V chunk: 8 rows x 128B (from Vt rows, global row stride 4096B)
        int row = c * 8 + (lane >> 3);
        int cb = ((lane & 7) * 16) ^ ((row & 7) << 4);
        async_ld16((const char*)Vg + (size_t)row * 4096 + (size_t)k0 * 2 + cb,
                   (char*)Vs[buf] + c * 1024);
      }
    }
  };

  stage(0, 0);
  __syncthreads();

  for (int s = 0; s < nk; ++s) {
    const int k0 = s * 64;
    if (s + 1 < nk) stage((s + 1) & 1, (s + 1) * 64);

    if (k0 < qw + 32) {  // not fully masked for this warp
      const int buf = s & 1;
      // ---- S^T = K . Q^T : two 32-key chunks
      f32x16 st[2] = {};
#pragma unroll
      for (int kc = 0; kc < 2; kc++) {
        int row = kc * 32 + lq;
        int swz = (row & 7) << 4;
        const char* kbase = (const char*)Ks[buf] + row * 256;
#pragma unroll
        for (int dc = 0; dc < 8; dc++) {
          short8 kf = *(const short8*)(kbase + ((dc * 32 + hi * 16) ^ swz));
          st[kc] = __builtin_amdgcn_mfma_f32_32x32x16_bf16(kf, qf[dc], st[kc], 0, 0, 0);
        }
      }
      // ---- scale (log2 domain) + causal mask + row max
      const float sc = 0.12751744416163417f;  // (1/sqrt(128)) * log2(e)
      float pm = -1e30f;
      const bool msk = (k0 + 63 > qw);
#pragma unroll
      for (int kc = 0; kc < 2; kc++)
#pragma unroll
        for (int r = 0; r < 16; r++) {
          float v = st[kc][r] * sc;
          if (msk) {
            int kg = k0 + kc * 32 + (r & 3) + 8 * (r >> 2) + 4 * hi;
            v = (kg <= qg) ? v : -1e30f;
          }
          st[kc][r] = v;
          pm = fmaxf(pm, v);
        }
      pm = fmaxf(pm, __shfl_xor(pm, 32));
      // ---- defer-max rescale (THR=8 in log2 domain)
      if (__any(pm > m + 8.f)) {
        float mnew = fmaxf(m, pm);
        float alpha = exp2f(m - mnew);
        m = mnew;
        l *= alpha;
        float al[16];
#pragma unroll
        for (int r = 0; r < 16; r++)
          al[r] = __shfl(alpha, (r & 3) + 8 * (r >> 2) + 4 * hi);
#pragma unroll
        for (int dc = 0; dc < 4; dc++)
#pragma unroll
          for (int r = 0; r < 16; r++) oacc[dc][r] *= al[r];
      }
      // ---- exp + row sum
      float rs = 0.f;
#pragma unroll
      for (int kc = 0; kc < 2; kc++)
#pragma unroll
        for (int r = 0; r < 16; r++) {
          float p = exp2f(st[kc][r] - m);
          st[kc][r] = p;
          rs += p;
        }
      rs += __shfl_xor(rs, 32);
      l += rs;
      // ---- pack P into PV A-frags (row=lane&31=q, k=ks*16+hi*8+j), exchange via lane^32
      short8 af[4];
#pragma unroll
      for (int kc = 0; kc < 2; kc++)
#pragma unroll
        for (int sb = 0; sb < 2; sb++) {
          int base = sb * 8;
          unsigned int a01 = cvt_pk_bf16(st[kc][base + 0], st[kc][base + 1]);
          unsigned int a23 = cvt_pk_bf16(st[kc][base + 2], st[kc][base + 3]);
          unsigned int b01 = cvt_pk_bf16(st[kc][base + 4], st[kc][base + 5]);
          unsigned int b23 = cvt_pk_bf16(st[kc][base + 6], st[kc][base + 7]);
          unsigned int xa01 = (unsigned int)__shfl_xor((int)a01, 32);
          unsigned int xa23 = (unsigned int)__shfl_xor((int)a23, 32);
          unsigned int xb01 = (unsigned int)__shfl_xor((int)b01, 32);
          unsigned int xb23 = (unsigned int)__shfl_xor((int)b23, 32);
          union { unsigned int u[4]; short8 s; } f;
          f.u[0] = hi ? xb01 : a01;
          f.u[1] = hi ? xb23 : a23;
          f.u[2] = hi ? b01 : xa01;
          f.u[3] = hi ? b23 : xa23;
          af[kc * 2 + sb] = f.s;
        }
      // ---- O += P . V  (B-frag from Vs rows = d, col=lane&31=d)
#pragma unroll
      for (int dc = 0; dc < 4; dc++) {
        int row = dc * 32 + lq;
        int swz = (row & 7) << 4;
        const char* vbase = (const char*)Vs[buf] + row * 128;
#pragma unroll
        for (int ks = 0; ks < 4; ks++) {
          short8 vf = *(const short8*)(vbase + ((ks * 32 + hi * 16) ^ swz));
          oacc[dc] = __builtin_amdgcn_mfma_f32_32x32x16_bf16(af[ks], vf, oacc[dc], 0, 0, 0);
        }
      }
    }
    __syncthreads();
  }

  // ---- epilogue: gather 1/l per O-row, write Y[b][t][h*128+d]
  float inv = 1.f / l;
  float iv[16];
#pragma unroll
  for (int r = 0; r < 16; r++)
    iv[r] = __shfl(inv, (r & 3) + 8 * (r >> 2) + 4 * hi);
#pragma unroll
  for (int dc = 0; dc < 4; dc++)
#pragma unroll
    for (int r = 0; r < 16; r++) {
      int t = qw + (r & 3) + 8 * (r >> 2) + 4 * hi;
      Y[(size_t)(b * 2048 + t) * 2048 + h * 128 + dc * 32 + lq] =
          __float2bfloat16(oacc[dc][r] * iv[r]);
    }
}

// ---------------------------------------------------------------- launcher
extern "C" void kernel_launch(void* const* d_in, const int* in_sizes, int n_in,
                              void* d_out, int out_size, void* d_ws, size_t ws_size,
                              hipStream_t stream) {
  (void)in_sizes; (void)n_in; (void)out_size; (void)ws_size;
  const float* x   = (const float*)d_in[0];
  const float* wq  = (const float*)d_in[1];
  const float* wk  = (const float*)d_in[2];
  const float* wv  = (const float*)d_in[3];
  const float* wo  = (const float*)d_in[4];
  const float* qnw = (const float*)d_in[5];
  const float* knw = (const float*)d_in[6];
  float* out = (float*)d_out;
  char* ws = (char*)d_ws;
  const size_t MB = 1u << 20;
  bf16*   xb  = (bf16*)(ws + 0 * MB);    // [4096][1024]
  bf16*   wt  = (bf16*)(ws + 8 * MB);    // [4096][1024]  rows: wq^T | wk^T | wv^T
  bf16*   wot = (bf16*)(ws + 16 * MB);   // [1024][2048]
  bf16*   qkv = (bf16*)(ws + 20 * MB);   // [4096][4096]
  float2* tab = (float2*)(ws + 52 * MB); // [2048][64]
  bf16*   Qh  = (bf16*)(ws + 53 * MB);   // [2][16][2048][128]
  bf16*   Kh  = (bf16*)(ws + 69 * MB);   // [2][8][2048][128]
  bf16*   Vtr = (bf16*)(ws + 77 * MB);   // [2][8][128][2048]  (V transposed)
  bf16*   Yb  = (bf16*)(ws + 85 * MB);   // [4096][2048]

  cvt_f32_bf16<<<4096, 256, 0, stream>>>(x, xb, 1048576);
  transpose_cvt<<<dim3(64, 32), 256, 0, stream>>>(wq, wt,               1024, 2048);
  transpose_cvt<<<dim3(32, 32), 256, 0, stream>>>(wk, wt + 2048 * 1024, 1024, 1024);
  transpose_cvt<<<dim3(32, 32), 256, 0, stream>>>(wv, wt + 3072 * 1024, 1024, 1024);
  transpose_cvt<<<dim3(32, 64), 256, 0, stream>>>(wo, wot,              2048, 1024);
  rope_tab<<<2048, 64, 0, stream>>>(tab);
  gemm_bt<false><<<dim3(32, 32), 256, 0, stream>>>(xb, wt, qkv, 4096, 4096, 1024);
  norm_rope<<<dim3(6, 4096), 256, 0, stream>>>(qkv, qnw, knw, tab, Qh, Kh);
  v_transpose<<<dim3(64, 4, 16), 256, 0, stream>>>(qkv, Vtr);
  flash_attn3<<<256, 512, 0, stream>>>(Qh, Kh, Vtr, Yb);
  gemm_bt<true><<<dim3(8, 32), 256, 0, stream>>>(Yb, wot, out, 4096, 1024, 2048);
}

// Round 4
// 214.804 us; speedup vs baseline: 1.0868x; 1.0868x over previous
//
#include <hip/hip_runtime.h>
#include <hip/hip_bf16.h>
#include <cstdint>
#include <cstddef>

using bf16 = __hip_bfloat16;
using short8 = __attribute__((ext_vector_type(8))) short;
using f32x4  = __attribute__((ext_vector_type(4))) float;
using f32x16 = __attribute__((ext_vector_type(16))) float;

#define DEVI __device__ __forceinline__

// async global->LDS, 16B per lane. LDS dest is wave-uniform base + lane*16.
DEVI void async_ld16(const void* g, void* l) {
  __builtin_amdgcn_global_load_lds(
      (const __attribute__((address_space(1))) unsigned int*)g,
      (__attribute__((address_space(3))) unsigned int*)l, 16, 0, 0);
}

DEVI unsigned int cvt_pk_bf16(float lo, float hi) {
  unsigned int r;
  asm("v_cvt_pk_bf16_f32 %0, %1, %2" : "=v"(r) : "v"(lo), "v"(hi));
  return r;
}

// ---------------------------------------------------------------- cvt f32->bf16
__global__ void cvt_f32_bf16(const float* __restrict__ in, bf16* __restrict__ out, int n4) {
  int i = blockIdx.x * blockDim.x + threadIdx.x;
  if (i >= n4) return;
  float4 v = ((const float4*)in)[i];
  union { bf16 h[4]; ushort4 u; } o;
  o.h[0] = __float2bfloat16(v.x);
  o.h[1] = __float2bfloat16(v.y);
  o.h[2] = __float2bfloat16(v.z);
  o.h[3] = __float2bfloat16(v.w);
  ((ushort4*)out)[i] = o.u;
}

// ------------------------------------------- transpose + cvt: in[K][N] -> out[N][K]
__global__ __launch_bounds__(256) void transpose_cvt(
    const float* __restrict__ in, bf16* __restrict__ out, int K, int N) {
  __shared__ float tile[32][33];
  int n0 = blockIdx.x * 32, k0 = blockIdx.y * 32;
  int tx = threadIdx.x & 31, ty = threadIdx.x >> 5;  // 32 x 8
#pragma unroll
  for (int i = 0; i < 32; i += 8)
    tile[ty + i][tx] = in[(size_t)(k0 + ty + i) * N + n0 + tx];
  __syncthreads();
#pragma unroll
  for (int i = 0; i < 32; i += 8)
    out[(size_t)(n0 + ty + i) * K + k0 + tx] = __float2bfloat16(tile[tx][ty + i]);
}

// ----------------------- V transpose: Vt[b*8+kvh][hd][t] <- qkv[b*2048+t][3072+kvh*128+hd]
__global__ __launch_bounds__(256) void v_transpose(
    const bf16* __restrict__ qkv, bf16* __restrict__ Vt) {
  __shared__ bf16 tile[32][34];
  int bk = blockIdx.z;                       // 0..15
  int t0 = blockIdx.x * 32, h0 = blockIdx.y * 32;
  int tx = threadIdx.x & 31, ty = threadIdx.x >> 5;  // 32 x 8
  int b = bk >> 3, kvh = bk & 7;
  const bf16* src = qkv + (size_t)(b * 2048) * 4096 + 3072 + kvh * 128;
#pragma unroll
  for (int i = 0; i < 32; i += 8)
    tile[ty + i][tx] = src[(size_t)(t0 + ty + i) * 4096 + h0 + tx];
  __syncthreads();
  bf16* dst = Vt + (size_t)bk * 128 * 2048;
#pragma unroll
  for (int i = 0; i < 32; i += 8)
    dst[(size_t)(h0 + ty + i) * 2048 + t0 + tx] = tile[tx][ty + i];
}

// ---------------------------------------------------------------- rope table
__global__ void rope_tab(float2* __restrict__ tab) {
  int t = blockIdx.x, i = threadIdx.x;  // T blocks x 64 threads
  float ex = -2.f * (float)i * (1.f / 128.f);
  float theta = exp2f(ex * 19.9315685693241741f);  // log2(1e6)
  float f = (float)t * theta;
  float sv, cv;
  sincosf(f, &sv, &cv);
  tab[t * 64 + i] = make_float2(cv, sv);
}

// ------------------------------------------------- GEMM: C[M][N] = A[M][K] * Bt[N][K]^T
template <bool OUT_F32>
__global__ __launch_bounds__(256) void gemm_bt(
    const bf16* __restrict__ A, const bf16* __restrict__ Bt,
    void* __restrict__ Cv, int M, int N, int K) {
  __shared__ alignas(16) bf16 As[128 * 64];
  __shared__ alignas(16) bf16 Bs[128 * 64];
  const int tid = threadIdx.x, lane = tid & 63, w = tid >> 6;
  const int wm = w >> 1, wn = w & 1;
  const int m0 = blockIdx.y * 128, n0 = blockIdx.x * 128;
  f32x4 acc[4][4] = {};

  const int srow = lane >> 3;          // row within 8-row slab
  const int scb  = (lane & 7) * 16;    // linear col byte

  for (int kt = 0; kt < K; kt += 64) {
#pragma unroll
    for (int i = 0; i < 4; i++) {
      int row = w * 32 + i * 8 + srow;
      int src_cb = scb ^ ((row & 7) << 4);
      async_ld16((const char*)(A  + (size_t)(m0 + row) * K + kt) + src_cb,
                 (char*)As + w * 4096 + i * 1024);
      async_ld16((const char*)(Bt + (size_t)(n0 + row) * K + kt) + src_cb,
                 (char*)Bs + w * 4096 + i * 1024);
    }
    __syncthreads();
#pragma unroll
    for (int ks = 0; ks < 2; ks++) {
      short8 af[4], bfr[4];
#pragma unroll
      for (int mi = 0; mi < 4; mi++) {
        int row = wm * 64 + mi * 16 + (lane & 15);
        int cb = (ks * 64 + (lane >> 4) * 16) ^ ((row & 7) << 4);
        af[mi] = *(const short8*)((const char*)As + row * 128 + cb);
      }
#pragma unroll
      for (int ni = 0; ni < 4; ni++) {
        int row = wn * 64 + ni * 16 + (lane & 15);
        int cb = (ks * 64 + (lane >> 4) * 16) ^ ((row & 7) << 4);
        bfr[ni] = *(const short8*)((const char*)Bs + row * 128 + cb);
      }
#pragma unroll
      for (int mi = 0; mi < 4; mi++)
#pragma unroll
        for (int ni = 0; ni < 4; ni++)
          acc[mi][ni] = __builtin_amdgcn_mfma_f32_16x16x32_bf16(af[mi], bfr[ni], acc[mi][ni], 0, 0, 0);
    }
    __syncthreads();
  }

  const int c0 = n0 + wn * 64 + (lane & 15);
  const int r0 = m0 + wm * 64 + (lane >> 4) * 4;
#pragma unroll
  for (int mi = 0; mi < 4; mi++)
#pragma unroll
    for (int ni = 0; ni < 4; ni++)
#pragma unroll
      for (int r = 0; r < 4; r++) {
        size_t idx = (size_t)(r0 + mi * 16 + r) * N + (c0 + ni * 16);
        float v = acc[mi][ni][r];
        if constexpr (OUT_F32) ((float*)Cv)[idx] = v;
        else                   ((bf16*)Cv)[idx] = __float2bfloat16(v);
      }
}

// ------------------------- RMSNorm + RoPE + relayout to [B][H][T][HD] bf16 (Q,K only)
__global__ __launch_bounds__(256) void norm_rope(
    const bf16* __restrict__ qkv, const float* __restrict__ qw, const float* __restrict__ kw,
    const float2* __restrict__ tab,
    bf16* __restrict__ Qh, bf16* __restrict__ Kh) {
  const int lane = threadIdx.x & 63;
  const int slot = blockIdx.x * 4 + (threadIdx.x >> 6);  // 0..23
  const int m = blockIdx.y;
  const int b = m >> 11, t = m & 2047;

  int type = slot < 16 ? 0 : 1;
  int h = type ? slot - 16 : slot;
  int col = type ? 2048 + h * 128 : h * 128;

  const bf16* src = qkv + (size_t)m * 4096 + col + lane * 2;
  bf16* dst = type
      ? Kh + ((size_t)(b * 8 + h) * 2048 + t) * 128 + lane * 2
      : Qh + ((size_t)(b * 16 + h) * 2048 + t) * 128 + lane * 2;

  float x0 = __bfloat162float(src[0]);
  float x1 = __bfloat162float(src[1]);

  float ss = x0 * x0 + x1 * x1;
#pragma unroll
  for (int o = 1; o < 64; o <<= 1) ss += __shfl_xor(ss, o);
  float rms = sqrtf(ss * (1.f / 128.f));
  float inv = 1.f / (rms + 1e-6f);
  const float* wn = type ? kw : qw;
  float n0 = wn[lane * 2] * x0 * inv;
  float n1 = wn[lane * 2 + 1] * x1 * inv;
  float2 cs = tab[t * 64 + lane];
  dst[0] = __float2bfloat16(n0 * cs.x - n1 * cs.y);
  dst[1] = __float2bfloat16(n0 * cs.y + n1 * cs.x);
}

// ------------------------------------ flash attention v4 (4-warp 32x32, balanced grid)
// 256 thr (4 warps x 32 q = 128-q tile), KVBLK=64, swapped QK^T, in-register softmax,
// defer-max, K/V double-buffered. Grid 512 = 2 blocks/CU: first 256 dispatched blocks
// are the LONG q-tiles (p=15..8), second 256 the SHORT (p=0..7), same bh -> each CU
// hosts a {long,short} pair totaling 34 kv-steps; bh grouped 4-per-XCD for L2.
__global__ __launch_bounds__(256, 2) void flash_attn4(
    const bf16* __restrict__ Qh, const bf16* __restrict__ Kh,
    const bf16* __restrict__ Vt, bf16* __restrict__ Y) {
  __shared__ alignas(16) bf16 Ks[2][64 * 128];   // [key][hd] rows 256B, XOR-swizzled
  __shared__ alignas(16) bf16 Vs[2][128 * 64];   // [hd][key] rows 128B, XOR-swizzled
  const int tid = threadIdx.x, lane = tid & 63, w = tid >> 6;
  const int hi = lane >> 5, lq = lane & 31;

  const int g = blockIdx.x;
  const int xcd = g & 7, r = g >> 3;             // r in [0,64)
  const int bh = xcd * 4 + (r & 3);
  const int p_idx = r >> 2;                      // [0,16)
  const int p = (p_idx < 8) ? (15 - p_idx) : (p_idx - 8);
  const int b = bh >> 4, h = bh & 15, kvh = h >> 1;

  const int q0 = p * 128, nk = 2 * p + 2, qw = q0 + w * 32;
  const int qg = qw + lq;  // this lane's q row (softmax owner)

  const bf16* Qg = Qh + (size_t)(b * 16 + h) * 2048 * 128;
  const bf16* Kg = Kh + (size_t)(b * 8 + kvh) * 2048 * 128;
  const bf16* Vg = Vt + (size_t)(b * 8 + kvh) * 128 * 2048;

  // Q fragments: B-operand of 32x32x16 (col=lane&31=q, k(d)=hi*8+j)
  short8 qf[8];
#pragma unroll
  for (int dc = 0; dc < 8; dc++)
    qf[dc] = *(const short8*)(Qg + (size_t)qg * 128 + dc * 16 + hi * 8);

  f32x16 oacc[4] = {};   // O[32q][128d]: col=lane&31=d, row=q=(r&3)+8*(r>>2)+4*hi
  float m = -1e30f, l = 0.f;

  auto stage = [&](int buf, int k0) {
#pragma unroll
    for (int i = 0; i < 4; i++) {
      int c = w * 4 + i;  // chunk 0..15
      {  // K chunk: 4 rows x 256B
        int row = c * 4 + (lane >> 4);
        int cb = ((lane & 15) * 16) ^ ((row & 7) << 4);
        async_ld16((const char*)Kg + (size_t)(k0 + row) * 256 + cb,
                   (char*)Ks[buf] + c * 1024);
      }
      {  // V chunk: 8 rows x 128B (from Vt rows, global row stride 4096B)
        int row = c * 8 + (lane >> 3);
        int cb = ((lane & 7) * 16) ^ ((row & 7) << 4);
        async_ld16((const char*)Vg + (size_t)row * 4096 + (size_t)k0 * 2 + cb,
                   (char*)Vs[buf] + c * 1024);
      }
    }
  };

  stage(0, 0);
  __syncthreads();

  for (int s = 0; s < nk; ++s) {
    const int k0 = s * 64;
    if (s + 1 < nk) stage((s + 1) & 1, (s + 1) * 64);

    if (k0 < qw + 32) {  // not fully masked for this warp
      const int buf = s & 1;
      // ---- S^T = K . Q^T : two 32-key chunks
      f32x16 st[2] = {};
#pragma unroll
      for (int kc = 0; kc < 2; kc++) {
        int row = kc * 32 + lq;
        int swz = (row & 7) << 4;
        const char* kbase = (const char*)Ks[buf] + row * 256;
#pragma unroll
        for (int dc = 0; dc < 8; dc++) {
          short8 kf = *(const short8*)(kbase + ((dc * 32 + hi * 16) ^ swz));
          st[kc] = __builtin_amdgcn_mfma_f32_32x32x16_bf16(kf, qf[dc], st[kc], 0, 0, 0);
        }
      }
      // ---- scale (log2 domain) + causal mask + row max
      const float sc = 0.12751744416163417f;  // (1/sqrt(128)) * log2(e)
      float pm = -1e30f;
      const bool msk = (k0 + 63 > qw);
#pragma unroll
      for (int kc = 0; kc < 2; kc++)
#pragma unroll
        for (int rr = 0; rr < 16; rr++) {
          float v = st[kc][rr] * sc;
          if (msk) {
            int kg = k0 + kc * 32 + (rr & 3) + 8 * (rr >> 2) + 4 * hi;
            v = (kg <= qg) ? v : -1e30f;
          }
          st[kc][rr] = v;
          pm = fmaxf(pm, v);
        }
      pm = fmaxf(pm, __shfl_xor(pm, 32));
      // ---- defer-max rescale (THR=8 in log2 domain)
      if (__any(pm > m + 8.f)) {
        float mnew = fmaxf(m, pm);
        float alpha = exp2f(m - mnew);
        m = mnew;
        l *= alpha;
        float al[16];
#pragma unroll
        for (int rr = 0; rr < 16; rr++)
          al[rr] = __shfl(alpha, (rr & 3) + 8 * (rr >> 2) + 4 * hi);
#pragma unroll
        for (int dc = 0; dc < 4; dc++)
#pragma unroll
          for (int rr = 0; rr < 16; rr++) oacc[dc][rr] *= al[rr];
      }
      // ---- exp + row sum
      float rs = 0.f;
#pragma unroll
      for (int kc = 0; kc < 2; kc++)
#pragma unroll
        for (int rr = 0; rr < 16; rr++) {
          float pv = exp2f(st[kc][rr] - m);
          st[kc][rr] = pv;
          rs += pv;
        }
      rs += __shfl_xor(rs, 32);
      l += rs;
      // ---- pack P into PV A-frags (row=lane&31=q, k=ks*16+hi*8+j), exchange via lane^32
      short8 af[4];
#pragma unroll
      for (int kc = 0; kc < 2; kc++)
#pragma unroll
        for (int sb = 0; sb < 2; sb++) {
          int base = sb * 8;
          unsigned int a01 = cvt_pk_bf16(st[kc][base + 0], st[kc][base + 1]);
          unsigned int a23 = cvt_pk_bf16(st[kc][base + 2], st[kc][base + 3]);
          unsigned int b01 = cvt_pk_bf16(st[kc][base + 4], st[kc][base + 5]);
          unsigned int b23 = cvt_pk_bf16(st[kc][base + 6], st[kc][base + 7]);
          unsigned int xa01 = (unsigned int)__shfl_xor((int)a01, 32);
          unsigned int xa23 = (unsigned int)__shfl_xor((int)a23, 32);
          unsigned int xb01 = (unsigned int)__shfl_xor((int)b01, 32);
          unsigned int xb23 = (unsigned int)__shfl_xor((int)b23, 32);
          union { unsigned int u[4]; short8 s; } f;
          f.u[0] = hi ? xb01 : a01;
          f.u[1] = hi ? xb23 : a23;
          f.u[2] = hi ? b01 : xa01;
          f.u[3] = hi ? b23 : xa23;
          af[kc * 2 + sb] = f.s;
        }
      // ---- O += P . V  (B-frag from Vs rows = d, col=lane&31=d)
#pragma unroll
      for (int dc = 0; dc < 4; dc++) {
        int row = dc * 32 + lq;
        int swz = (row & 7) << 4;
        const char* vbase = (const char*)Vs[buf] + row * 128;
#pragma unroll
        for (int ks = 0; ks < 4; ks++) {
          short8 vf = *(const short8*)(vbase + ((ks * 32 + hi * 16) ^ swz));
          oacc[dc] = __builtin_amdgcn_mfma_f32_32x32x16_bf16(af[ks], vf, oacc[dc], 0, 0, 0);
        }
      }
    }
    __syncthreads();
  }

  // ---- epilogue: gather 1/l per O-row, write Y[b][t][h*128+d]
  float inv = 1.f / l;
  float iv[16];
#pragma unroll
  for (int rr = 0; rr < 16; rr++)
    iv[rr] = __shfl(inv, (rr & 3) + 8 * (rr >> 2) + 4 * hi);
#pragma unroll
  for (int dc = 0; dc < 4; dc++)
#pragma unroll
    for (int rr = 0; rr < 16; rr++) {
      int t = qw + (rr & 3) + 8 * (rr >> 2) + 4 * hi;
      Y[(size_t)(b * 2048 + t) * 2048 + h * 128 + dc * 32 + lq] =
          __float2bfloat16(oacc[dc][rr] * iv[rr]);
    }
}

// ---------------------------------------------------------------- launcher
extern "C" void kernel_launch(void* const* d_in, const int* in_sizes, int n_in,
                              void* d_out, int out_size, void* d_ws, size_t ws_size,
                              hipStream_t stream) {
  (void)in_sizes; (void)n_in; (void)out_size; (void)ws_size;
  const float* x   = (const float*)d_in[0];
  const float* wq  = (const float*)d_in[1];
  const float* wk  = (const float*)d_in[2];
  const float* wv  = (const float*)d_in[3];
  const float* wo  = (const float*)d_in[4];
  const float* qnw = (const float*)d_in[5];
  const float* knw = (const float*)d_in[6];
  float* out = (float*)d_out;
  char* ws = (char*)d_ws;
  const size_t MB = 1u << 20;
  bf16*   xb  = (bf16*)(ws + 0 * MB);    // [4096][1024]
  bf16*   wt  = (bf16*)(ws + 8 * MB);    // [4096][1024]  rows: wq^T | wk^T | wv^T
  bf16*   wot = (bf16*)(ws + 16 * MB);   // [1024][2048]
  bf16*   qkv = (bf16*)(ws + 20 * MB);   // [4096][4096]
  float2* tab = (float2*)(ws + 52 * MB); // [2048][64]
  bf16*   Qh  = (bf16*)(ws + 53 * MB);   // [2][16][2048][128]
  bf16*   Kh  = (bf16*)(ws + 69 * MB);   // [2][8][2048][128]
  bf16*   Vtr = (bf16*)(ws + 77 * MB);   // [2][8][128][2048]  (V transposed)
  bf16*   Yb  = (bf16*)(ws + 85 * MB);   // [4096][2048]

  cvt_f32_bf16<<<4096, 256, 0, stream>>>(x, xb, 1048576);
  transpose_cvt<<<dim3(64, 32), 256, 0, stream>>>(wq, wt,               1024, 2048);
  transpose_cvt<<<dim3(32, 32), 256, 0, stream>>>(wk, wt + 2048 * 1024, 1024, 1024);
  transpose_cvt<<<dim3(32, 32), 256, 0, stream>>>(wv, wt + 3072 * 1024, 1024, 1024);
  transpose_cvt<<<dim3(32, 64), 256, 0, stream>>>(wo, wot,              2048, 1024);
  rope_tab<<<2048, 64, 0, stream>>>(tab);
  gemm_bt<false><<<dim3(32, 32), 256, 0, stream>>>(xb, wt, qkv, 4096, 4096, 1024);
  norm_rope<<<dim3(6, 4096), 256, 0, stream>>>(qkv, qnw, knw, tab, Qh, Kh);
  v_transpose<<<dim3(64, 4, 16), 256, 0, stream>>>(qkv, Vtr);
  flash_attn4<<<512, 256, 0, stream>>>(Qh, Kh, Vtr, Yb);
  gemm_bt<true><<<dim3(8, 32), 256, 0, stream>>>(Yb, wot, out, 4096, 1024, 2048);
}

// Round 5
// 213.153 us; speedup vs baseline: 1.0953x; 1.0077x over previous
//
#include <hip/hip_runtime.h>
#include <hip/hip_bf16.h>
#include <cstdint>
#include <cstddef>

using bf16 = __hip_bfloat16;
using short8 = __attribute__((ext_vector_type(8))) short;
using f32x4  = __attribute__((ext_vector_type(4))) float;
using f32x16 = __attribute__((ext_vector_type(16))) float;

#define DEVI __device__ __forceinline__

// async global->LDS, 16B per lane. LDS dest is wave-uniform base + lane*16.
DEVI void async_ld16(const void* g, void* l) {
  __builtin_amdgcn_global_load_lds(
      (const __attribute__((address_space(1))) unsigned int*)g,
      (__attribute__((address_space(3))) unsigned int*)l, 16, 0, 0);
}

DEVI unsigned int cvt_pk_bf16(float lo, float hi) {
  unsigned int r;
  asm("v_cvt_pk_bf16_f32 %0, %1, %2" : "=v"(r) : "v"(lo), "v"(hi));
  return r;
}

// ---------------------------------------------------------------- cvt f32->bf16
__global__ void cvt_f32_bf16(const float* __restrict__ in, bf16* __restrict__ out, int n4) {
  int i = blockIdx.x * blockDim.x + threadIdx.x;
  if (i >= n4) return;
  float4 v = ((const float4*)in)[i];
  union { bf16 h[4]; ushort4 u; } o;
  o.h[0] = __float2bfloat16(v.x);
  o.h[1] = __float2bfloat16(v.y);
  o.h[2] = __float2bfloat16(v.z);
  o.h[3] = __float2bfloat16(v.w);
  ((ushort4*)out)[i] = o.u;
}

// ------------------------------------------- transpose + cvt: in[K][N] -> out[N][K]
__global__ __launch_bounds__(256) void transpose_cvt(
    const float* __restrict__ in, bf16* __restrict__ out, int K, int N) {
  __shared__ float tile[32][33];
  int n0 = blockIdx.x * 32, k0 = blockIdx.y * 32;
  int tx = threadIdx.x & 31, ty = threadIdx.x >> 5;  // 32 x 8
#pragma unroll
  for (int i = 0; i < 32; i += 8)
    tile[ty + i][tx] = in[(size_t)(k0 + ty + i) * N + n0 + tx];
  __syncthreads();
#pragma unroll
  for (int i = 0; i < 32; i += 8)
    out[(size_t)(n0 + ty + i) * K + k0 + tx] = __float2bfloat16(tile[tx][ty + i]);
}

// ----------------------- V transpose: Vt[b*8+kvh][hd][t] <- qkv[b*2048+t][3072+kvh*128+hd]
__global__ __launch_bounds__(256) void v_transpose(
    const bf16* __restrict__ qkv, bf16* __restrict__ Vt) {
  __shared__ bf16 tile[32][34];
  int bk = blockIdx.z;                       // 0..15
  int t0 = blockIdx.x * 32, h0 = blockIdx.y * 32;
  int tx = threadIdx.x & 31, ty = threadIdx.x >> 5;  // 32 x 8
  int b = bk >> 3, kvh = bk & 7;
  const bf16* src = qkv + (size_t)(b * 2048) * 4096 + 3072 + kvh * 128;
#pragma unroll
  for (int i = 0; i < 32; i += 8)
    tile[ty + i][tx] = src[(size_t)(t0 + ty + i) * 4096 + h0 + tx];
  __syncthreads();
  bf16* dst = Vt + (size_t)bk * 128 * 2048;
#pragma unroll
  for (int i = 0; i < 32; i += 8)
    dst[(size_t)(h0 + ty + i) * 2048 + t0 + tx] = tile[tx][ty + i];
}

// ---------------------------------------------------------------- rope table
__global__ void rope_tab(float2* __restrict__ tab) {
  int t = blockIdx.x, i = threadIdx.x;  // T blocks x 64 threads
  float ex = -2.f * (float)i * (1.f / 128.f);
  float theta = exp2f(ex * 19.9315685693241741f);  // log2(1e6)
  float f = (float)t * theta;
  float sv, cv;
  sincosf(f, &sv, &cv);
  tab[t * 64 + i] = make_float2(cv, sv);
}

// ------------------------------------------------- GEMM: C[M][N] = A[M][K] * Bt[N][K]^T
template <bool OUT_F32>
__global__ __launch_bounds__(256) void gemm_bt(
    const bf16* __restrict__ A, const bf16* __restrict__ Bt,
    void* __restrict__ Cv, int M, int N, int K) {
  __shared__ alignas(16) bf16 As[128 * 64];
  __shared__ alignas(16) bf16 Bs[128 * 64];
  const int tid = threadIdx.x, lane = tid & 63, w = tid >> 6;
  const int wm = w >> 1, wn = w & 1;
  const int m0 = blockIdx.y * 128, n0 = blockIdx.x * 128;
  f32x4 acc[4][4] = {};

  const int srow = lane >> 3;          // row within 8-row slab
  const int scb  = (lane & 7) * 16;    // linear col byte

  for (int kt = 0; kt < K; kt += 64) {
#pragma unroll
    for (int i = 0; i < 4; i++) {
      int row = w * 32 + i * 8 + srow;
      int src_cb = scb ^ ((row & 7) << 4);
      async_ld16((const char*)(A  + (size_t)(m0 + row) * K + kt) + src_cb,
                 (char*)As + w * 4096 + i * 1024);
      async_ld16((const char*)(Bt + (size_t)(n0 + row) * K + kt) + src_cb,
                 (char*)Bs + w * 4096 + i * 1024);
    }
    __syncthreads();
#pragma unroll
    for (int ks = 0; ks < 2; ks++) {
      short8 af[4], bfr[4];
#pragma unroll
      for (int mi = 0; mi < 4; mi++) {
        int row = wm * 64 + mi * 16 + (lane & 15);
        int cb = (ks * 64 + (lane >> 4) * 16) ^ ((row & 7) << 4);
        af[mi] = *(const short8*)((const char*)As + row * 128 + cb);
      }
#pragma unroll
      for (int ni = 0; ni < 4; ni++) {
        int row = wn * 64 + ni * 16 + (lane & 15);
        int cb = (ks * 64 + (lane >> 4) * 16) ^ ((row & 7) << 4);
        bfr[ni] = *(const short8*)((const char*)Bs + row * 128 + cb);
      }
#pragma unroll
      for (int mi = 0; mi < 4; mi++)
#pragma unroll
        for (int ni = 0; ni < 4; ni++)
          acc[mi][ni] = __builtin_amdgcn_mfma_f32_16x16x32_bf16(af[mi], bfr[ni], acc[mi][ni], 0, 0, 0);
    }
    __syncthreads();
  }

  const int c0 = n0 + wn * 64 + (lane & 15);
  const int r0 = m0 + wm * 64 + (lane >> 4) * 4;
#pragma unroll
  for (int mi = 0; mi < 4; mi++)
#pragma unroll
    for (int ni = 0; ni < 4; ni++)
#pragma unroll
      for (int r = 0; r < 4; r++) {
        size_t idx = (size_t)(r0 + mi * 16 + r) * N + (c0 + ni * 16);
        float v = acc[mi][ni][r];
        if constexpr (OUT_F32) ((float*)Cv)[idx] = v;
        else                   ((bf16*)Cv)[idx] = __float2bfloat16(v);
      }
}

// ------------------------- RMSNorm + RoPE + relayout to [B][H][T][HD] bf16 (Q,K only)
__global__ __launch_bounds__(256) void norm_rope(
    const bf16* __restrict__ qkv, const float* __restrict__ qw, const float* __restrict__ kw,
    const float2* __restrict__ tab,
    bf16* __restrict__ Qh, bf16* __restrict__ Kh) {
  const int lane = threadIdx.x & 63;
  const int slot = blockIdx.x * 4 + (threadIdx.x >> 6);  // 0..23
  const int m = blockIdx.y;
  const int b = m >> 11, t = m & 2047;

  int type = slot < 16 ? 0 : 1;
  int h = type ? slot - 16 : slot;
  int col = type ? 2048 + h * 128 : h * 128;

  const bf16* src = qkv + (size_t)m * 4096 + col + lane * 2;
  bf16* dst = type
      ? Kh + ((size_t)(b * 8 + h) * 2048 + t) * 128 + lane * 2
      : Qh + ((size_t)(b * 16 + h) * 2048 + t) * 128 + lane * 2;

  float x0 = __bfloat162float(src[0]);
  float x1 = __bfloat162float(src[1]);

  float ss = x0 * x0 + x1 * x1;
#pragma unroll
  for (int o = 1; o < 64; o <<= 1) ss += __shfl_xor(ss, o);
  float rms = sqrtf(ss * (1.f / 128.f));
  float inv = 1.f / (rms + 1e-6f);
  const float* wn = type ? kw : qw;
  float n0 = wn[lane * 2] * x0 * inv;
  float n1 = wn[lane * 2 + 1] * x1 * inv;
  float2 cs = tab[t * 64 + lane];
  dst[0] = __float2bfloat16(n0 * cs.x - n1 * cs.y);
  dst[1] = __float2bfloat16(n0 * cs.y + n1 * cs.x);
}

// -------------------- flash attention v5 (8-warp supertile pair, counted-vmcnt pipeline)
// Block = (bh, p): q-tiles {15-p (warps 0-3), p (warps 4-7)}; tile B's KV range is a
// prefix of tile A's -> shared K/V staging. Grid 256 = 1 block/CU, deterministic balance.
// Raw s_barrier + asm vmcnt(4): prefetch for s+1 stays in flight across barriers (T4).
__global__ __launch_bounds__(512, 2) void flash_attn5(
    const bf16* __restrict__ Qh, const bf16* __restrict__ Kh,
    const bf16* __restrict__ Vt, bf16* __restrict__ Y) {
  __shared__ alignas(16) bf16 Ks[2][64 * 128];   // [key][hd] rows 256B, XOR-swizzled
  __shared__ alignas(16) bf16 Vs[2][128 * 64];   // [hd][key] rows 128B, XOR-swizzled
  const int tid = threadIdx.x, lane = tid & 63, w = tid >> 6;
  const int hi = lane >> 5, lq = lane & 31;

  // grid 256: xcd = g&7 owns 4 bh (K/V L2-resident); p = pair index
  const int g = blockIdx.x;
  const int bh = (g & 7) * 4 + ((g >> 3) & 3);
  const int p  = g >> 5;                         // 0..7
  const int b = bh >> 4, h = bh & 15, kvh = h >> 1;

  const int tA = 15 - p;                         // long tile (warps 0-3)
  const int nk = 2 * tA + 2;                     // kv-steps (covers both tiles)
  const int wg = w >> 2, wl = w & 3;
  const int tq = (wg ? p : tA) * 128;
  const int qw = tq + wl * 32;
  const int qg = qw + lq;                        // this lane's q row (softmax owner)

  const bf16* Qg = Qh + (size_t)(b * 16 + h) * 2048 * 128;
  const bf16* Kg = Kh + (size_t)(b * 8 + kvh) * 2048 * 128;
  const bf16* Vg = Vt + (size_t)(b * 8 + kvh) * 128 * 2048;

  // Q fragments: B-operand of 32x32x16 (col=lane&31=q, k(d)=hi*8+j)
  short8 qf[8];
#pragma unroll
  for (int dc = 0; dc < 8; dc++)
    qf[dc] = *(const short8*)(Qg + (size_t)qg * 128 + dc * 16 + hi * 8);

  f32x16 oacc[4] = {};   // O[32q][128d]: col=lane&31=d, row=q=(r&3)+8*(r>>2)+4*hi
  float m = -1e30f, l = 0.f;

  // staging shared by all 8 warps: 2 K-chunks + 2 V-chunks per warp
  auto stage = [&](int buf, int k0) {
#pragma unroll
    for (int i = 0; i < 2; i++) {
      int c = w * 2 + i;  // chunk 0..15
      {  // K chunk: 4 rows x 256B
        int row = c * 4 + (lane >> 4);
        int cb = ((lane & 15) * 16) ^ ((row & 7) << 4);
        async_ld16((const char*)Kg + (size_t)(k0 + row) * 256 + cb,
                   (char*)Ks[buf] + c * 1024);
      }
      {  // V chunk: 8 rows x 128B (from Vt rows, global row stride 4096B)
        int row = c * 8 + (lane >> 3);
        int cb = ((lane & 7) * 16) ^ ((row & 7) << 4);
        async_ld16((const char*)Vg + (size_t)row * 4096 + (size_t)k0 * 2 + cb,
                   (char*)Vs[buf] + c * 1024);
      }
    }
  };

  stage(0, 0);
  stage(1, 64);   // nk >= 18 always

  for (int s = 0; s < nk; ++s) {
    const int k0 = s * 64;
    // loads(s) are the oldest 4 outstanding; loads(s+1) (newest 4) stay in flight
    if (s + 1 < nk) asm volatile("s_waitcnt vmcnt(4)" ::: "memory");
    else            asm volatile("s_waitcnt vmcnt(0)" ::: "memory");
    __builtin_amdgcn_s_barrier();

    if (k0 < qw + 32) {  // warp-predicated: past this warp's diagonal -> idle
      const int buf = s & 1;
      // ---- S^T = K . Q^T : two 32-key chunks
      f32x16 st[2] = {};
#pragma unroll
      for (int kc = 0; kc < 2; kc++) {
        int row = kc * 32 + lq;
        int swz = (row & 7) << 4;
        const char* kbase = (const char*)Ks[buf] + row * 256;
#pragma unroll
        for (int dc = 0; dc < 8; dc++) {
          short8 kf = *(const short8*)(kbase + ((dc * 32 + hi * 16) ^ swz));
          st[kc] = __builtin_amdgcn_mfma_f32_32x32x16_bf16(kf, qf[dc], st[kc], 0, 0, 0);
        }
      }
      // ---- scale (log2 domain) + causal mask + row max
      const float sc = 0.12751744416163417f;  // (1/sqrt(128)) * log2(e)
      float pm = -1e30f;
      const bool msk = (k0 + 63 > qw);
#pragma unroll
      for (int kc = 0; kc < 2; kc++)
#pragma unroll
        for (int rr = 0; rr < 16; rr++) {
          float v = st[kc][rr] * sc;
          if (msk) {
            int kg = k0 + kc * 32 + (rr & 3) + 8 * (rr >> 2) + 4 * hi;
            v = (kg <= qg) ? v : -1e30f;
          }
          st[kc][rr] = v;
          pm = fmaxf(pm, v);
        }
      pm = fmaxf(pm, __shfl_xor(pm, 32));
      // ---- defer-max rescale (THR=8 in log2 domain)
      if (__any(pm > m + 8.f)) {
        float mnew = fmaxf(m, pm);
        float alpha = exp2f(m - mnew);
        m = mnew;
        l *= alpha;
        float al[16];
#pragma unroll
        for (int rr = 0; rr < 16; rr++)
          al[rr] = __shfl(alpha, (rr & 3) + 8 * (rr >> 2) + 4 * hi);
#pragma unroll
        for (int dc = 0; dc < 4; dc++)
#pragma unroll
          for (int rr = 0; rr < 16; rr++) oacc[dc][rr] *= al[rr];
      }
      // ---- exp + row sum
      float rs = 0.f;
#pragma unroll
      for (int kc = 0; kc < 2; kc++)
#pragma unroll
        for (int rr = 0; rr < 16; rr++) {
          float pv = exp2f(st[kc][rr] - m);
          st[kc][rr] = pv;
          rs += pv;
        }
      rs += __shfl_xor(rs, 32);
      l += rs;
      // ---- pack P into PV A-frags (row=lane&31=q, k=ks*16+hi*8+j), exchange via lane^32
      short8 af[4];
#pragma unroll
      for (int kc = 0; kc < 2; kc++)
#pragma unroll
        for (int sb = 0; sb < 2; sb++) {
          int base = sb * 8;
          unsigned int a01 = cvt_pk_bf16(st[kc][base + 0], st[kc][base + 1]);
          unsigned int a23 = cvt_pk_bf16(st[kc][base + 2], st[kc][base + 3]);
          unsigned int b01 = cvt_pk_bf16(st[kc][base + 4], st[kc][base + 5]);
          unsigned int b23 = cvt_pk_bf16(st[kc][base + 6], st[kc][base + 7]);
          unsigned int xa01 = (unsigned int)__shfl_xor((int)a01, 32);
          unsigned int xa23 = (unsigned int)__shfl_xor((int)a23, 32);
          unsigned int xb01 = (unsigned int)__shfl_xor((int)b01, 32);
          unsigned int xb23 = (unsigned int)__shfl_xor((int)b23, 32);
          union { unsigned int u[4]; short8 s; } f;
          f.u[0] = hi ? xb01 : a01;
          f.u[1] = hi ? xb23 : a23;
          f.u[2] = hi ? b01 : xa01;
          f.u[3] = hi ? b23 : xa23;
          af[kc * 2 + sb] = f.s;
        }
      // ---- O += P . V  (B-frag from Vs rows = d, col=lane&31=d)
#pragma unroll
      for (int dc = 0; dc < 4; dc++) {
        int row = dc * 32 + lq;
        int swz = (row & 7) << 4;
        const char* vbase = (const char*)Vs[buf] + row * 128;
#pragma unroll
        for (int ks = 0; ks < 4; ks++) {
          short8 vf = *(const short8*)(vbase + ((ks * 32 + hi * 16) ^ swz));
          oacc[dc] = __builtin_amdgcn_mfma_f32_32x32x16_bf16(af[ks], vf, oacc[dc], 0, 0, 0);
        }
      }
    }

    __builtin_amdgcn_s_barrier();              // all waves done reading buf s
    __builtin_amdgcn_sched_barrier(0);
    if (s + 2 < nk) stage(s & 1, (s + 2) * 64);  // overwrite just-freed buffer
  }

  // ---- epilogue: gather 1/l per O-row, write Y[b][t][h*128+d]
  float inv = 1.f / l;
  float iv[16];
#pragma unroll
  for (int rr = 0; rr < 16; rr++)
    iv[rr] = __shfl(inv, (rr & 3) + 8 * (rr >> 2) + 4 * hi);
#pragma unroll
  for (int dc = 0; dc < 4; dc++)
#pragma unroll
    for (int rr = 0; rr < 16; rr++) {
      int t = qw + (rr & 3) + 8 * (rr >> 2) + 4 * hi;
      Y[(size_t)(b * 2048 + t) * 2048 + h * 128 + dc * 32 + lq] =
          __float2bfloat16(oacc[dc][rr] * iv[rr]);
    }
}

// ---------------------------------------------------------------- launcher
extern "C" void kernel_launch(void* const* d_in, const int* in_sizes, int n_in,
                              void* d_out, int out_size, void* d_ws, size_t ws_size,
                              hipStream_t stream) {
  (void)in_sizes; (void)n_in; (void)out_size; (void)ws_size;
  const float* x   = (const float*)d_in[0];
  const float* wq  = (const float*)d_in[1];
  const float* wk  = (const float*)d_in[2];
  const float* wv  = (const float*)d_in[3];
  const float* wo  = (const float*)d_in[4];
  const float* qnw = (const float*)d_in[5];
  const float* knw = (const float*)d_in[6];
  float* out = (float*)d_out;
  char* ws = (char*)d_ws;
  const size_t MB = 1u << 20;
  bf16*   xb  = (bf16*)(ws + 0 * MB);    // [4096][1024]
  bf16*   wt  = (bf16*)(ws + 8 * MB);    // [4096][1024]  rows: wq^T | wk^T | wv^T
  bf16*   wot = (bf16*)(ws + 16 * MB);   // [1024][2048]
  bf16*   qkv = (bf16*)(ws + 20 * MB);   // [4096][4096]
  float2* tab = (float2*)(ws + 52 * MB); // [2048][64]
  bf16*   Qh  = (bf16*)(ws + 53 * MB);   // [2][16][2048][128]
  bf16*   Kh  = (bf16*)(ws + 69 * MB);   // [2][8][2048][128]
  bf16*   Vtr = (bf16*)(ws + 77 * MB);   // [2][8][128][2048]  (V transposed)
  bf16*   Yb  = (bf16*)(ws + 85 * MB);   // [4096][2048]

  cvt_f32_bf16<<<4096, 256, 0, stream>>>(x, xb, 1048576);
  transpose_cvt<<<dim3(64, 32), 256, 0, stream>>>(wq, wt,               1024, 2048);
  transpose_cvt<<<dim3(32, 32), 256, 0, stream>>>(wk, wt + 2048 * 1024, 1024, 1024);
  transpose_cvt<<<dim3(32, 32), 256, 0, stream>>>(wv, wt + 3072 * 1024, 1024, 1024);
  transpose_cvt<<<dim3(32, 64), 256, 0, stream>>>(wo, wot,              2048, 1024);
  rope_tab<<<2048, 64, 0, stream>>>(tab);
  gemm_bt<false><<<dim3(32, 32), 256, 0, stream>>>(xb, wt, qkv, 4096, 4096, 1024);
  norm_rope<<<dim3(6, 4096), 256, 0, stream>>>(qkv, qnw, knw, tab, Qh, Kh);
  v_transpose<<<dim3(64, 4, 16), 256, 0, stream>>>(qkv, Vtr);
  flash_attn5<<<256, 512, 0, stream>>>(Qh, Kh, Vtr, Yb);
  gemm_bt<true><<<dim3(8, 32), 256, 0, stream>>>(Yb, wot, out, 4096, 1024, 2048);
}

// Round 6
// 212.513 us; speedup vs baseline: 1.0986x; 1.0030x over previous
//
#include <hip/hip_runtime.h>
#include <hip/hip_bf16.h>
#include <cstdint>
#include <cstddef>

using bf16 = __hip_bfloat16;
using short8 = __attribute__((ext_vector_type(8))) short;
using f32x4  = __attribute__((ext_vector_type(4))) float;
using f32x16 = __attribute__((ext_vector_type(16))) float;

#define DEVI __device__ __forceinline__

// async global->LDS, 16B per lane. LDS dest is wave-uniform base + lane*16.
DEVI void async_ld16(const void* g, void* l) {
  __builtin_amdgcn_global_load_lds(
      (const __attribute__((address_space(1))) unsigned int*)g,
      (__attribute__((address_space(3))) unsigned int*)l, 16, 0, 0);
}

DEVI unsigned int cvt_pk_bf16(float lo, float hi) {
  unsigned int r;
  asm("v_cvt_pk_bf16_f32 %0, %1, %2" : "=v"(r) : "v"(lo), "v"(hi));
  return r;
}

// ---------------------------------------------------------------- cvt f32->bf16
__global__ void cvt_f32_bf16(const float* __restrict__ in, bf16* __restrict__ out, int n4) {
  int i = blockIdx.x * blockDim.x + threadIdx.x;
  if (i >= n4) return;
  float4 v = ((const float4*)in)[i];
  union { bf16 h[4]; ushort4 u; } o;
  o.h[0] = __float2bfloat16(v.x);
  o.h[1] = __float2bfloat16(v.y);
  o.h[2] = __float2bfloat16(v.z);
  o.h[3] = __float2bfloat16(v.w);
  ((ushort4*)out)[i] = o.u;
}

// ------------------------------------------- transpose + cvt: in[K][N] -> out[N][K]
__global__ __launch_bounds__(256) void transpose_cvt(
    const float* __restrict__ in, bf16* __restrict__ out, int K, int N) {
  __shared__ float tile[32][33];
  int n0 = blockIdx.x * 32, k0 = blockIdx.y * 32;
  int tx = threadIdx.x & 31, ty = threadIdx.x >> 5;  // 32 x 8
#pragma unroll
  for (int i = 0; i < 32; i += 8)
    tile[ty + i][tx] = in[(size_t)(k0 + ty + i) * N + n0 + tx];
  __syncthreads();
#pragma unroll
  for (int i = 0; i < 32; i += 8)
    out[(size_t)(n0 + ty + i) * K + k0 + tx] = __float2bfloat16(tile[tx][ty + i]);
}

// ------------------- fused wq/wk/wv transpose: wt[4096][1024] = [wq^T | wk^T | wv^T]
__global__ __launch_bounds__(256) void transpose_cvt3(
    const float* __restrict__ wq, const float* __restrict__ wk,
    const float* __restrict__ wv, bf16* __restrict__ wt) {
  __shared__ float tile[32][33];
  int z = blockIdx.z;
  const float* src; int N, coff, roff;
  if (z < 2)       { src = wq; N = 2048; coff = z * 1024; roff = z * 1024; }
  else if (z == 2) { src = wk; N = 1024; coff = 0;        roff = 2048; }
  else             { src = wv; N = 1024; coff = 0;        roff = 3072; }
  int n0 = coff + blockIdx.x * 32, k0 = blockIdx.y * 32;
  int tx = threadIdx.x & 31, ty = threadIdx.x >> 5;
#pragma unroll
  for (int i = 0; i < 32; i += 8)
    tile[ty + i][tx] = src[(size_t)(k0 + ty + i) * N + n0 + tx];
  __syncthreads();
#pragma unroll
  for (int i = 0; i < 32; i += 8)
    wt[(size_t)(roff + blockIdx.x * 32 + ty + i) * 1024 + k0 + tx] =
        __float2bfloat16(tile[tx][ty + i]);
}

// ----------------------- V transpose: Vt[b*8+kvh][hd][t] <- qkv[b*2048+t][3072+kvh*128+hd]
__global__ __launch_bounds__(256) void v_transpose(
    const bf16* __restrict__ qkv, bf16* __restrict__ Vt) {
  __shared__ bf16 tile[32][34];
  int bk = blockIdx.z;                       // 0..15
  int t0 = blockIdx.x * 32, h0 = blockIdx.y * 32;
  int tx = threadIdx.x & 31, ty = threadIdx.x >> 5;  // 32 x 8
  int b = bk >> 3, kvh = bk & 7;
  const bf16* src = qkv + (size_t)(b * 2048) * 4096 + 3072 + kvh * 128;
#pragma unroll
  for (int i = 0; i < 32; i += 8)
    tile[ty + i][tx] = src[(size_t)(t0 + ty + i) * 4096 + h0 + tx];
  __syncthreads();
  bf16* dst = Vt + (size_t)bk * 128 * 2048;
#pragma unroll
  for (int i = 0; i < 32; i += 8)
    dst[(size_t)(h0 + ty + i) * 2048 + t0 + tx] = tile[tx][ty + i];
}

// ---------------------------------------------------------------- rope table
__global__ void rope_tab(float2* __restrict__ tab) {
  int t = blockIdx.x, i = threadIdx.x;  // T blocks x 64 threads
  float ex = -2.f * (float)i * (1.f / 128.f);
  float theta = exp2f(ex * 19.9315685693241741f);  // log2(1e6)
  float f = (float)t * theta;
  float sv, cv;
  sincosf(f, &sv, &cv);
  tab[t * 64 + i] = make_float2(cv, sv);
}

// --------------------- 256x256 8-wave phase-split GEMM (T3+T4+T5): C = A * Bt^T, bf16
// BK=64, 4 mi-phases/K-tile, counted vmcnt(8) depth-2 staging via global_load_lds.
__global__ __launch_bounds__(512, 1) void gemm256(
    const bf16* __restrict__ A, const bf16* __restrict__ Bt,
    bf16* __restrict__ C, int M, int N, int K) {
  __shared__ alignas(16) bf16 As[2][256 * 64];   // rows 128B, byte ^= (row&7)<<4
  __shared__ alignas(16) bf16 Bs[2][256 * 64];
  const int tid = threadIdx.x, lane = tid & 63, w = tid >> 6;
  const int hi = lane >> 5, lq = lane & 31;
  const int wr = w >> 2, wc = w & 3;             // 2x4 wave grid
  const int m0 = blockIdx.y * 256, n0 = blockIdx.x * 256;
  const int nt = K >> 6;

  f32x16 acc[4][2] = {};   // [mi][ni]: out rows wr*128+mi*32, cols wc*64+ni*32

  auto stage = [&](int buf, int kt) {
#pragma unroll
    for (int i = 0; i < 4; i++) {
      int c = tid + i * 512;                     // 16B chunk 0..2047
      int row = c >> 3;
      int cb = ((c & 7) * 16) ^ ((row & 7) << 4);
      async_ld16((const char*)(A + (size_t)(m0 + row) * K + kt * 64) + cb,
                 (char*)As[buf] + i * 8192 + tid * 16);
      async_ld16((const char*)(Bt + (size_t)(n0 + row) * K + kt * 64) + cb,
                 (char*)Bs[buf] + i * 8192 + tid * 16);
    }
  };

  stage(0, 0);
  stage(1, 1);

  for (int t = 0; t < nt; ++t) {
    const int buf = t & 1;
    if (t + 1 < nt) asm volatile("s_waitcnt vmcnt(8)" ::: "memory");
    else            asm volatile("s_waitcnt vmcnt(0)" ::: "memory");
    __builtin_amdgcn_s_barrier();                // buf fully staged for all waves

    const char* Ab = (const char*)As[buf];
    const char* Bb = (const char*)Bs[buf];
    short8 bfr[2][4];
#pragma unroll
    for (int mi = 0; mi < 4; mi++) {
      // phase mi: issue ds_reads (overlaps other waves' MFMA), then barrier+compute
      if (mi == 0) {
#pragma unroll
        for (int ni = 0; ni < 2; ni++) {
          int row = wc * 64 + ni * 32 + lq;
          int swz = (row & 7) << 4;
#pragma unroll
          for (int ks = 0; ks < 4; ks++)
            bfr[ni][ks] = *(const short8*)(Bb + row * 128 + ((ks * 32 + hi * 16) ^ swz));
        }
      }
      short8 af[4];
      {
        int row = wr * 128 + mi * 32 + lq;
        int swz = (row & 7) << 4;
#pragma unroll
        for (int ks = 0; ks < 4; ks++)
          af[ks] = *(const short8*)(Ab + row * 128 + ((ks * 32 + hi * 16) ^ swz));
      }
      __builtin_amdgcn_s_barrier();
      asm volatile("s_waitcnt lgkmcnt(0)" ::: "memory");
      __builtin_amdgcn_sched_barrier(0);
      __builtin_amdgcn_s_setprio(1);
#pragma unroll
      for (int ni = 0; ni < 2; ni++)
#pragma unroll
        for (int ks = 0; ks < 4; ks++)
          acc[mi][ni] = __builtin_amdgcn_mfma_f32_32x32x16_bf16(af[ks], bfr[ni][ks],
                                                               acc[mi][ni], 0, 0, 0);
      __builtin_amdgcn_s_setprio(0);
      __builtin_amdgcn_s_barrier();
    }
    __builtin_amdgcn_sched_barrier(0);
    if (t + 2 < nt) stage(buf, t + 2);           // overwrite just-freed buffer
  }

  // epilogue: C/D layout col=lane&31, row=(r&3)+8*(r>>2)+4*hi
  const int cn = n0 + wc * 64 + lq;
#pragma unroll
  for (int mi = 0; mi < 4; mi++)
#pragma unroll
    for (int ni = 0; ni < 2; ni++)
#pragma unroll
      for (int r = 0; r < 16; r++) {
        int row = m0 + wr * 128 + mi * 32 + (r & 3) + 8 * (r >> 2) + 4 * hi;
        C[(size_t)row * N + cn + ni * 32] = __float2bfloat16(acc[mi][ni][r]);
      }
}

// ------------------------------------------------- GEMM: C[M][N] = A[M][K] * Bt[N][K]^T
template <bool OUT_F32>
__global__ __launch_bounds__(256) void gemm_bt(
    const bf16* __restrict__ A, const bf16* __restrict__ Bt,
    void* __restrict__ Cv, int M, int N, int K) {
  __shared__ alignas(16) bf16 As[128 * 64];
  __shared__ alignas(16) bf16 Bs[128 * 64];
  const int tid = threadIdx.x, lane = tid & 63, w = tid >> 6;
  const int wm = w >> 1, wn = w & 1;
  const int m0 = blockIdx.y * 128, n0 = blockIdx.x * 128;
  f32x4 acc[4][4] = {};

  const int srow = lane >> 3;          // row within 8-row slab
  const int scb  = (lane & 7) * 16;    // linear col byte

  for (int kt = 0; kt < K; kt += 64) {
#pragma unroll
    for (int i = 0; i < 4; i++) {
      int row = w * 32 + i * 8 + srow;
      int src_cb = scb ^ ((row & 7) << 4);
      async_ld16((const char*)(A  + (size_t)(m0 + row) * K + kt) + src_cb,
                 (char*)As + w * 4096 + i * 1024);
      async_ld16((const char*)(Bt + (size_t)(n0 + row) * K + kt) + src_cb,
                 (char*)Bs + w * 4096 + i * 1024);
    }
    __syncthreads();
#pragma unroll
    for (int ks = 0; ks < 2; ks++) {
      short8 af[4], bfr[4];
#pragma unroll
      for (int mi = 0; mi < 4; mi++) {
        int row = wm * 64 + mi * 16 + (lane & 15);
        int cb = (ks * 64 + (lane >> 4) * 16) ^ ((row & 7) << 4);
        af[mi] = *(const short8*)((const char*)As + row * 128 + cb);
      }
#pragma unroll
      for (int ni = 0; ni < 4; ni++) {
        int row = wn * 64 + ni * 16 + (lane & 15);
        int cb = (ks * 64 + (lane >> 4) * 16) ^ ((row & 7) << 4);
        bfr[ni] = *(const short8*)((const char*)Bs + row * 128 + cb);
      }
#pragma unroll
      for (int mi = 0; mi < 4; mi++)
#pragma unroll
        for (int ni = 0; ni < 4; ni++)
          acc[mi][ni] = __builtin_amdgcn_mfma_f32_16x16x32_bf16(af[mi], bfr[ni], acc[mi][ni], 0, 0, 0);
    }
    __syncthreads();
  }

  const int c0 = n0 + wn * 64 + (lane & 15);
  const int r0 = m0 + wm * 64 + (lane >> 4) * 4;
#pragma unroll
  for (int mi = 0; mi < 4; mi++)
#pragma unroll
    for (int ni = 0; ni < 4; ni++)
#pragma unroll
      for (int r = 0; r < 4; r++) {
        size_t idx = (size_t)(r0 + mi * 16 + r) * N + (c0 + ni * 16);
        float v = acc[mi][ni][r];
        if constexpr (OUT_F32) ((float*)Cv)[idx] = v;
        else                   ((bf16*)Cv)[idx] = __float2bfloat16(v);
      }
}

// ------------------------- RMSNorm + RoPE + relayout to [B][H][T][HD] bf16 (Q,K only)
__global__ __launch_bounds__(256) void norm_rope(
    const bf16* __restrict__ qkv, const float* __restrict__ qw, const float* __restrict__ kw,
    const float2* __restrict__ tab,
    bf16* __restrict__ Qh, bf16* __restrict__ Kh) {
  const int lane = threadIdx.x & 63;
  const int slot = blockIdx.x * 4 + (threadIdx.x >> 6);  // 0..23
  const int m = blockIdx.y;
  const int b = m >> 11, t = m & 2047;

  int type = slot < 16 ? 0 : 1;
  int h = type ? slot - 16 : slot;
  int col = type ? 2048 + h * 128 : h * 128;

  const bf16* src = qkv + (size_t)m * 4096 + col + lane * 2;
  bf16* dst = type
      ? Kh + ((size_t)(b * 8 + h) * 2048 + t) * 128 + lane * 2
      : Qh + ((size_t)(b * 16 + h) * 2048 + t) * 128 + lane * 2;

  float x0 = __bfloat162float(src[0]);
  float x1 = __bfloat162float(src[1]);

  float ss = x0 * x0 + x1 * x1;
#pragma unroll
  for (int o = 1; o < 64; o <<= 1) ss += __shfl_xor(ss, o);
  float rms = sqrtf(ss * (1.f / 128.f));
  float inv = 1.f / (rms + 1e-6f);
  const float* wn = type ? kw : qw;
  float n0 = wn[lane * 2] * x0 * inv;
  float n1 = wn[lane * 2 + 1] * x1 * inv;
  float2 cs = tab[t * 64 + lane];
  dst[0] = __float2bfloat16(n0 * cs.x - n1 * cs.y);
  dst[1] = __float2bfloat16(n0 * cs.y + n1 * cs.x);
}

// -------------------- flash attention v5 (8-warp supertile pair, counted-vmcnt pipeline)
__global__ __launch_bounds__(512, 2) void flash_attn5(
    const bf16* __restrict__ Qh, const bf16* __restrict__ Kh,
    const bf16* __restrict__ Vt, bf16* __restrict__ Y) {
  __shared__ alignas(16) bf16 Ks[2][64 * 128];   // [key][hd] rows 256B, XOR-swizzled
  __shared__ alignas(16) bf16 Vs[2][128 * 64];   // [hd][key] rows 128B, XOR-swizzled
  const int tid = threadIdx.x, lane = tid & 63, w = tid >> 6;
  const int hi = lane >> 5, lq = lane & 31;

  const int g = blockIdx.x;
  const int bh = (g & 7) * 4 + ((g >> 3) & 3);
  const int p  = g >> 5;                         // 0..7
  const int b = bh >> 4, h = bh & 15, kvh = h >> 1;

  const int tA = 15 - p;                         // long tile (warps 0-3)
  const int nk = 2 * tA + 2;
  const int wg = w >> 2, wl = w & 3;
  const int tq = (wg ? p : tA) * 128;
  const int qw = tq + wl * 32;
  const int qg = qw + lq;

  const bf16* Qg = Qh + (size_t)(b * 16 + h) * 2048 * 128;
  const bf16* Kg = Kh + (size_t)(b * 8 + kvh) * 2048 * 128;
  const bf16* Vg = Vt + (size_t)(b * 8 + kvh) * 128 * 2048;

  short8 qf[8];
#pragma unroll
  for (int dc = 0; dc < 8; dc++)
    qf[dc] = *(const short8*)(Qg + (size_t)qg * 128 + dc * 16 + hi * 8);

  f32x16 oacc[4] = {};
  float m = -1e30f, l = 0.f;

  auto stage = [&](int buf, int k0) {
#pragma unroll
    for (int i = 0; i < 2; i++) {
      int c = w * 2 + i;
      {
        int row = c * 4 + (lane >> 4);
        int cb = ((lane & 15) * 16) ^ ((row & 7) << 4);
        async_ld16((const char*)Kg + (size_t)(k0 + row) * 256 + cb,
                   (char*)Ks[buf] + c * 1024);
      }
      {
        int row = c * 8 + (lane >> 3);
        int cb = ((lane & 7) * 16) ^ ((row & 7) << 4);
        async_ld16((const char*)Vg + (size_t)row * 4096 + (size_t)k0 * 2 + cb,
                   (char*)Vs[buf] + c * 1024);
      }
    }
  };

  stage(0, 0);
  stage(1, 64);

  for (int s = 0; s < nk; ++s) {
    const int k0 = s * 64;
    if (s + 1 < nk) asm volatile("s_waitcnt vmcnt(4)" ::: "memory");
    else            asm volatile("s_waitcnt vmcnt(0)" ::: "memory");
    __builtin_amdgcn_s_barrier();

    if (k0 < qw + 32) {
      const int buf = s & 1;
      f32x16 st[2] = {};
      __builtin_amdgcn_s_setprio(1);
#pragma unroll
      for (int kc = 0; kc < 2; kc++) {
        int row = kc * 32 + lq;
        int swz = (row & 7) << 4;
        const char* kbase = (const char*)Ks[buf] + row * 256;
#pragma unroll
        for (int dc = 0; dc < 8; dc++) {
          short8 kf = *(const short8*)(kbase + ((dc * 32 + hi * 16) ^ swz));
          st[kc] = __builtin_amdgcn_mfma_f32_32x32x16_bf16(kf, qf[dc], st[kc], 0, 0, 0);
        }
      }
      __builtin_amdgcn_s_setprio(0);
      const float sc = 0.12751744416163417f;  // (1/sqrt(128)) * log2(e)
      float pm = -1e30f;
      const bool msk = (k0 + 63 > qw);
#pragma unroll
      for (int kc = 0; kc < 2; kc++)
#pragma unroll
        for (int rr = 0; rr < 16; rr++) {
          float v = st[kc][rr] * sc;
          if (msk) {
            int kg = k0 + kc * 32 + (rr & 3) + 8 * (rr >> 2) + 4 * hi;
            v = (kg <= qg) ? v : -1e30f;
          }
          st[kc][rr] = v;
          pm = fmaxf(pm, v);
        }
      pm = fmaxf(pm, __shfl_xor(pm, 32));
      if (__any(pm > m + 8.f)) {
        float mnew = fmaxf(m, pm);
        float alpha = exp2f(m - mnew);
        m = mnew;
        l *= alpha;
        float al[16];
#pragma unroll
        for (int rr = 0; rr < 16; rr++)
          al[rr] = __shfl(alpha, (rr & 3) + 8 * (rr >> 2) + 4 * hi);
#pragma unroll
        for (int dc = 0; dc < 4; dc++)
#pragma unroll
          for (int rr = 0; rr < 16; rr++) oacc[dc][rr] *= al[rr];
      }
      float rs = 0.f;
#pragma unroll
      for (int kc = 0; kc < 2; kc++)
#pragma unroll
        for (int rr = 0; rr < 16; rr++) {
          float pv = exp2f(st[kc][rr] - m);
          st[kc][rr] = pv;
          rs += pv;
        }
      rs += __shfl_xor(rs, 32);
      l += rs;
      short8 af[4];
#pragma unroll
      for (int kc = 0; kc < 2; kc++)
#pragma unroll
        for (int sb = 0; sb < 2; sb++) {
          int base = sb * 8;
          unsigned int a01 = cvt_pk_bf16(st[kc][base + 0], st[kc][base + 1]);
          unsigned int a23 = cvt_pk_bf16(st[kc][base + 2], st[kc][base + 3]);
          unsigned int b01 = cvt_pk_bf16(st[kc][base + 4], st[kc][base + 5]);
          unsigned int b23 = cvt_pk_bf16(st[kc][base + 6], st[kc][base + 7]);
          unsigned int xa01 = (unsigned int)__shfl_xor((int)a01, 32);
          unsigned int xa23 = (unsigned int)__shfl_xor((int)a23, 32);
          unsigned int xb01 = (unsigned int)__shfl_xor((int)b01, 32);
          unsigned int xb23 = (unsigned int)__shfl_xor((int)b23, 32);
          union { unsigned int u[4]; short8 s; } f;
          f.u[0] = hi ? xb01 : a01;
          f.u[1] = hi ? xb23 : a23;
          f.u[2] = hi ? b01 : xa01;
          f.u[3] = hi ? b23 : xa23;
          af[kc * 2 + sb] = f.s;
        }
      __builtin_amdgcn_s_setprio(1);
#pragma unroll
      for (int dc = 0; dc < 4; dc++) {
        int row = dc * 32 + lq;
        int swz = (row & 7) << 4;
        const char* vbase = (const char*)Vs[buf] + row * 128;
#pragma unroll
        for (int ks = 0; ks < 4; ks++) {
          short8 vf = *(const short8*)(vbase + ((ks * 32 + hi * 16) ^ swz));
          oacc[dc] = __builtin_amdgcn_mfma_f32_32x32x16_bf16(af[ks], vf, oacc[dc], 0, 0, 0);
        }
      }
      __builtin_amdgcn_s_setprio(0);
    }

    __builtin_amdgcn_s_barrier();
    __builtin_amdgcn_sched_barrier(0);
    if (s + 2 < nk) stage(s & 1, (s + 2) * 64);
  }

  float inv = 1.f / l;
  float iv[16];
#pragma unroll
  for (int rr = 0; rr < 16; rr++)
    iv[rr] = __shfl(inv, (rr & 3) + 8 * (rr >> 2) + 4 * hi);
#pragma unroll
  for (int dc = 0; dc < 4; dc++)
#pragma unroll
    for (int rr = 0; rr < 16; rr++) {
      int t = qw + (rr & 3) + 8 * (rr >> 2) + 4 * hi;
      Y[(size_t)(b * 2048 + t) * 2048 + h * 128 + dc * 32 + lq] =
          __float2bfloat16(oacc[dc][rr] * iv[rr]);
    }
}

// ---------------------------------------------------------------- launcher
extern "C" void kernel_launch(void* const* d_in, const int* in_sizes, int n_in,
                              void* d_out, int out_size, void* d_ws, size_t ws_size,
                              hipStream_t stream) {
  (void)in_sizes; (void)n_in; (void)out_size; (void)ws_size;
  const float* x   = (const float*)d_in[0];
  const float* wq  = (const float*)d_in[1];
  const float* wk  = (const float*)d_in[2];
  const float* wv  = (const float*)d_in[3];
  const float* wo  = (const float*)d_in[4];
  const float* qnw = (const float*)d_in[5];
  const float* knw = (const float*)d_in[6];
  float* out = (float*)d_out;
  char* ws = (char*)d_ws;
  const size_t MB = 1u << 20;
  bf16*   xb  = (bf16*)(ws + 0 * MB);    // [4096][1024]
  bf16*   wt  = (bf16*)(ws + 8 * MB);    // [4096][1024]  rows: wq^T | wk^T | wv^T
  bf16*   wot = (bf16*)(ws + 16 * MB);   // [1024][2048]
  bf16*   qkv = (bf16*)(ws + 20 * MB);   // [4096][4096]
  float2* tab = (float2*)(ws + 52 * MB); // [2048][64]
  bf16*   Qh  = (bf16*)(ws + 53 * MB);   // [2][16][2048][128]
  bf16*   Kh  = (bf16*)(ws + 69 * MB);   // [2][8][2048][128]
  bf16*   Vtr = (bf16*)(ws + 77 * MB);   // [2][8][128][2048]  (V transposed)
  bf16*   Yb  = (bf16*)(ws + 85 * MB);   // [4096][2048]

  cvt_f32_bf16<<<4096, 256, 0, stream>>>(x, xb, 1048576);
  transpose_cvt3<<<dim3(32, 32, 4), 256, 0, stream>>>(wq, wk, wv, wt);
  transpose_cvt<<<dim3(32, 64), 256, 0, stream>>>(wo, wot, 2048, 1024);
  rope_tab<<<2048, 64, 0, stream>>>(tab);
  gemm256<<<dim3(16, 16), 512, 0, stream>>>(xb, wt, qkv, 4096, 4096, 1024);
  norm_rope<<<dim3(6, 4096), 256, 0, stream>>>(qkv, qnw, knw, tab, Qh, Kh);
  v_transpose<<<dim3(64, 4, 16), 256, 0, stream>>>(qkv, Vtr);
  flash_attn5<<<256, 512, 0, stream>>>(Qh, Kh, Vtr, Yb);
  gemm_bt<true><<<dim3(8, 32), 256, 0, stream>>>(Yb, wot, out, 4096, 1024, 2048);
}

// Round 7
// 195.447 us; speedup vs baseline: 1.1945x; 1.0873x over previous
//
#include <hip/hip_runtime.h>
#include <hip/hip_bf16.h>
#include <cstdint>
#include <cstddef>

using bf16 = __hip_bfloat16;
using short8 = __attribute__((ext_vector_type(8))) short;
using f32x4  = __attribute__((ext_vector_type(4))) float;
using f32x16 = __attribute__((ext_vector_type(16))) float;

#define DEVI __device__ __forceinline__

// async global->LDS, 16B per lane. LDS dest is wave-uniform base + lane*16.
DEVI void async_ld16(const void* g, void* l) {
  __builtin_amdgcn_global_load_lds(
      (const __attribute__((address_space(1))) unsigned int*)g,
      (__attribute__((address_space(3))) unsigned int*)l, 16, 0, 0);
}

DEVI unsigned int cvt_pk_bf16(float lo, float hi) {
  unsigned int r;
  asm("v_cvt_pk_bf16_f32 %0, %1, %2" : "=v"(r) : "v"(lo), "v"(hi));
  return r;
}

// ---------------------------------------------------------------- cvt f32->bf16
__global__ void cvt_f32_bf16(const float* __restrict__ in, bf16* __restrict__ out, int n4) {
  int i = blockIdx.x * blockDim.x + threadIdx.x;
  if (i >= n4) return;
  float4 v = ((const float4*)in)[i];
  union { bf16 h[4]; ushort4 u; } o;
  o.h[0] = __float2bfloat16(v.x);
  o.h[1] = __float2bfloat16(v.y);
  o.h[2] = __float2bfloat16(v.z);
  o.h[3] = __float2bfloat16(v.w);
  ((ushort4*)out)[i] = o.u;
}

// ------------------------------------------- transpose + cvt: in[K][N] -> out[N][K]
__global__ __launch_bounds__(256) void transpose_cvt(
    const float* __restrict__ in, bf16* __restrict__ out, int K, int N) {
  __shared__ float tile[32][33];
  int n0 = blockIdx.x * 32, k0 = blockIdx.y * 32;
  int tx = threadIdx.x & 31, ty = threadIdx.x >> 5;  // 32 x 8
#pragma unroll
  for (int i = 0; i < 32; i += 8)
    tile[ty + i][tx] = in[(size_t)(k0 + ty + i) * N + n0 + tx];
  __syncthreads();
#pragma unroll
  for (int i = 0; i < 32; i += 8)
    out[(size_t)(n0 + ty + i) * K + k0 + tx] = __float2bfloat16(tile[tx][ty + i]);
}

// ------------------- fused wq/wk/wv transpose: wt[4096][1024] = [wq^T | wk^T | wv^T]
__global__ __launch_bounds__(256) void transpose_cvt3(
    const float* __restrict__ wq, const float* __restrict__ wk,
    const float* __restrict__ wv, bf16* __restrict__ wt) {
  __shared__ float tile[32][33];
  int z = blockIdx.z;
  const float* src; int N, coff, roff;
  if (z < 2)       { src = wq; N = 2048; coff = z * 1024; roff = z * 1024; }
  else if (z == 2) { src = wk; N = 1024; coff = 0;        roff = 2048; }
  else             { src = wv; N = 1024; coff = 0;        roff = 3072; }
  int n0 = coff + blockIdx.x * 32, k0 = blockIdx.y * 32;
  int tx = threadIdx.x & 31, ty = threadIdx.x >> 5;
#pragma unroll
  for (int i = 0; i < 32; i += 8)
    tile[ty + i][tx] = src[(size_t)(k0 + ty + i) * N + n0 + tx];
  __syncthreads();
#pragma unroll
  for (int i = 0; i < 32; i += 8)
    wt[(size_t)(roff + blockIdx.x * 32 + ty + i) * 1024 + k0 + tx] =
        __float2bfloat16(tile[tx][ty + i]);
}

// ----------------------- V transpose: Vt[b*8+kvh][hd][t] <- qkv[b*2048+t][3072+kvh*128+hd]
__global__ __launch_bounds__(256) void v_transpose(
    const bf16* __restrict__ qkv, bf16* __restrict__ Vt) {
  __shared__ bf16 tile[32][34];
  int bk = blockIdx.z;                       // 0..15
  int t0 = blockIdx.x * 32, h0 = blockIdx.y * 32;
  int tx = threadIdx.x & 31, ty = threadIdx.x >> 5;  // 32 x 8
  int b = bk >> 3, kvh = bk & 7;
  const bf16* src = qkv + (size_t)(b * 2048) * 4096 + 3072 + kvh * 128;
#pragma unroll
  for (int i = 0; i < 32; i += 8)
    tile[ty + i][tx] = src[(size_t)(t0 + ty + i) * 4096 + h0 + tx];
  __syncthreads();
  bf16* dst = Vt + (size_t)bk * 128 * 2048;
#pragma unroll
  for (int i = 0; i < 32; i += 8)
    dst[(size_t)(h0 + ty + i) * 2048 + t0 + tx] = tile[tx][ty + i];
}

// ---------------------------------------------------------------- rope table
__global__ void rope_tab(float2* __restrict__ tab) {
  int t = blockIdx.x, i = threadIdx.x;  // T blocks x 64 threads
  float ex = -2.f * (float)i * (1.f / 128.f);
  float theta = exp2f(ex * 19.9315685693241741f);  // log2(1e6)
  float f = (float)t * theta;
  float sv, cv;
  sincosf(f, &sv, &cv);
  tab[t * 64 + i] = make_float2(cv, sv);
}

// --------------------- 256x256 8-wave GEMM, 2-barrier/K-tile + counted vmcnt(8)
__global__ __launch_bounds__(512, 1) void gemm256(
    const bf16* __restrict__ A, const bf16* __restrict__ Bt,
    bf16* __restrict__ C, int M, int N, int K) {
  __shared__ alignas(16) bf16 As[2][256 * 64];   // rows 128B, byte ^= (row&7)<<4
  __shared__ alignas(16) bf16 Bs[2][256 * 64];
  const int tid = threadIdx.x, lane = tid & 63;
  const int w = tid >> 6;
  const int hi = lane >> 5, lq = lane & 31;
  const int wr = w >> 2, wc = w & 3;             // 2x4 wave grid
  const int m0 = blockIdx.y * 256, n0 = blockIdx.x * 256;
  const int nt = K >> 6;

  f32x16 acc[4][2] = {};   // [mi][ni]: out rows wr*128+mi*32, cols wc*64+ni*32

  auto stage = [&](int buf, int kt) {
#pragma unroll
    for (int i = 0; i < 4; i++) {
      int c = tid + i * 512;                     // 16B chunk 0..2047
      int row = c >> 3;
      int cb = ((c & 7) * 16) ^ ((row & 7) << 4);
      async_ld16((const char*)(A + (size_t)(m0 + row) * K + kt * 64) + cb,
                 (char*)As[buf] + i * 8192 + tid * 16);
      async_ld16((const char*)(Bt + (size_t)(n0 + row) * K + kt * 64) + cb,
                 (char*)Bs[buf] + i * 8192 + tid * 16);
    }
  };

  stage(0, 0);
  stage(1, 1);

  for (int t = 0; t < nt; ++t) {
    const int buf = t & 1;
    if (t + 1 < nt) asm volatile("s_waitcnt vmcnt(8)" ::: "memory");
    else            asm volatile("s_waitcnt vmcnt(0)" ::: "memory");
    __builtin_amdgcn_s_barrier();                // buf fully staged for all waves

    const char* Ab = (const char*)As[buf];
    const char* Bb = (const char*)Bs[buf];
    short8 bfr[2][4];
#pragma unroll
    for (int ni = 0; ni < 2; ni++) {
      int row = wc * 64 + ni * 32 + lq;
      int swz = (row & 7) << 4;
#pragma unroll
      for (int ks = 0; ks < 4; ks++)
        bfr[ni][ks] = *(const short8*)(Bb + row * 128 + ((ks * 32 + hi * 16) ^ swz));
    }
#pragma unroll
    for (int mi = 0; mi < 4; mi++) {
      short8 af[4];
      int row = wr * 128 + mi * 32 + lq;
      int swz = (row & 7) << 4;
#pragma unroll
      for (int ks = 0; ks < 4; ks++)
        af[ks] = *(const short8*)(Ab + row * 128 + ((ks * 32 + hi * 16) ^ swz));
#pragma unroll
      for (int ni = 0; ni < 2; ni++)
#pragma unroll
        for (int ks = 0; ks < 4; ks++)
          acc[mi][ni] = __builtin_amdgcn_mfma_f32_32x32x16_bf16(af[ks], bfr[ni][ks],
                                                               acc[mi][ni], 0, 0, 0);
    }
    __builtin_amdgcn_s_barrier();                // all waves done reading buf
    __builtin_amdgcn_sched_barrier(0);
    if (t + 2 < nt) stage(buf, t + 2);           // overwrite just-freed buffer
  }

  // epilogue: C/D layout col=lane&31, row=(r&3)+8*(r>>2)+4*hi
  const int cn = n0 + wc * 64 + lq;
#pragma unroll
  for (int mi = 0; mi < 4; mi++)
#pragma unroll
    for (int ni = 0; ni < 2; ni++)
#pragma unroll
      for (int r = 0; r < 16; r++) {
        int row = m0 + wr * 128 + mi * 32 + (r & 3) + 8 * (r >> 2) + 4 * hi;
        C[(size_t)row * N + cn + ni * 32] = __float2bfloat16(acc[mi][ni][r]);
      }
}

// ------------------------------------------------- GEMM: C[M][N] = A[M][K] * Bt[N][K]^T
template <bool OUT_F32>
__global__ __launch_bounds__(256) void gemm_bt(
    const bf16* __restrict__ A, const bf16* __restrict__ Bt,
    void* __restrict__ Cv, int M, int N, int K) {
  __shared__ alignas(16) bf16 As[128 * 64];
  __shared__ alignas(16) bf16 Bs[128 * 64];
  const int tid = threadIdx.x, lane = tid & 63, w = tid >> 6;
  const int wm = w >> 1, wn = w & 1;
  const int m0 = blockIdx.y * 128, n0 = blockIdx.x * 128;
  f32x4 acc[4][4] = {};

  const int srow = lane >> 3;          // row within 8-row slab
  const int scb  = (lane & 7) * 16;    // linear col byte

  for (int kt = 0; kt < K; kt += 64) {
#pragma unroll
    for (int i = 0; i < 4; i++) {
      int row = w * 32 + i * 8 + srow;
      int src_cb = scb ^ ((row & 7) << 4);
      async_ld16((const char*)(A  + (size_t)(m0 + row) * K + kt) + src_cb,
                 (char*)As + w * 4096 + i * 1024);
      async_ld16((const char*)(Bt + (size_t)(n0 + row) * K + kt) + src_cb,
                 (char*)Bs + w * 4096 + i * 1024);
    }
    __syncthreads();
#pragma unroll
    for (int ks = 0; ks < 2; ks++) {
      short8 af[4], bfr[4];
#pragma unroll
      for (int mi = 0; mi < 4; mi++) {
        int row = wm * 64 + mi * 16 + (lane & 15);
        int cb = (ks * 64 + (lane >> 4) * 16) ^ ((row & 7) << 4);
        af[mi] = *(const short8*)((const char*)As + row * 128 + cb);
      }
#pragma unroll
      for (int ni = 0; ni < 4; ni++) {
        int row = wn * 64 + ni * 16 + (lane & 15);
        int cb = (ks * 64 + (lane >> 4) * 16) ^ ((row & 7) << 4);
        bfr[ni] = *(const short8*)((const char*)Bs + row * 128 + cb);
      }
#pragma unroll
      for (int mi = 0; mi < 4; mi++)
#pragma unroll
        for (int ni = 0; ni < 4; ni++)
          acc[mi][ni] = __builtin_amdgcn_mfma_f32_16x16x32_bf16(af[mi], bfr[ni], acc[mi][ni], 0, 0, 0);
    }
    __syncthreads();
  }

  const int c0 = n0 + wn * 64 + (lane & 15);
  const int r0 = m0 + wm * 64 + (lane >> 4) * 4;
#pragma unroll
  for (int mi = 0; mi < 4; mi++)
#pragma unroll
    for (int ni = 0; ni < 4; ni++)
#pragma unroll
      for (int r = 0; r < 4; r++) {
        size_t idx = (size_t)(r0 + mi * 16 + r) * N + (c0 + ni * 16);
        float v = acc[mi][ni][r];
        if constexpr (OUT_F32) ((float*)Cv)[idx] = v;
        else                   ((bf16*)Cv)[idx] = __float2bfloat16(v);
      }
}

// ---------- RMSNorm + RoPE + relayout, vectorized 16B/lane: 16-lane group per head row
__global__ __launch_bounds__(256) void norm_rope(
    const bf16* __restrict__ qkv, const float* __restrict__ qw, const float* __restrict__ kw,
    const float2* __restrict__ tab,
    bf16* __restrict__ Qh, bf16* __restrict__ Kh) {
  const int w = threadIdx.x >> 6, lane = threadIdx.x & 63;
  const int grp = lane >> 4, l = lane & 15;
  const int flat = blockIdx.x * 16 + w * 4 + grp;  // [0, 98304) = 4096 m x 24 slots
  const int m = flat / 24, slot = flat - m * 24;
  const int b = m >> 11, t = m & 2047;

  const int type = slot >= 16;
  const int h = type ? slot - 16 : slot;
  const int col = type ? 2048 + h * 128 : h * 128;

  union { short8 s; bf16 h[8]; } u;
  u.s = *(const short8*)(qkv + (size_t)m * 4096 + col + l * 8);
  float x[8];
#pragma unroll
  for (int j = 0; j < 8; j++) x[j] = __bfloat162float(u.h[j]);

  float ss = 0.f;
#pragma unroll
  for (int j = 0; j < 8; j++) ss += x[j] * x[j];
#pragma unroll
  for (int o = 1; o < 16; o <<= 1) ss += __shfl_xor(ss, o);
  float rms = sqrtf(ss * (1.f / 128.f));
  float inv = 1.f / (rms + 1e-6f);

  const float* wn = type ? kw : qw;
  float4 w0 = *(const float4*)(wn + l * 8);
  float4 w1 = *(const float4*)(wn + l * 8 + 4);
  float wv[8] = {w0.x, w0.y, w0.z, w0.w, w1.x, w1.y, w1.z, w1.w};

  const float4* tb = (const float4*)(tab + t * 64 + l * 4);
  float4 t0 = tb[0], t1 = tb[1];
  float cs[8] = {t0.x, t0.y, t0.z, t0.w, t1.x, t1.y, t1.z, t1.w};  // (c,s) x4 pairs

  union { short8 s; bf16 h[8]; } o;
#pragma unroll
  for (int i = 0; i < 4; i++) {
    float re = wv[2 * i] * x[2 * i] * inv;
    float im = wv[2 * i + 1] * x[2 * i + 1] * inv;
    float c = cs[2 * i], s = cs[2 * i + 1];
    o.h[2 * i]     = __float2bfloat16(re * c - im * s);
    o.h[2 * i + 1] = __float2bfloat16(re * s + im * c);
  }
  bf16* dst = type
      ? Kh + ((size_t)(b * 8 + h) * 2048 + t) * 128 + l * 8
      : Qh + ((size_t)(b * 16 + h) * 2048 + t) * 128 + l * 8;
  *(short8*)dst = o.s;
}

// -------------------- flash attention v7 (supertile pair, counted vmcnt, tree reduce)
__global__ __launch_bounds__(512, 2) void flash_attn7(
    const bf16* __restrict__ Qh, const bf16* __restrict__ Kh,
    const bf16* __restrict__ Vt, bf16* __restrict__ Y) {
  __shared__ alignas(16) bf16 Ks[2][64 * 128];   // [key][hd] rows 256B, XOR-swizzled
  __shared__ alignas(16) bf16 Vs[2][128 * 64];   // [hd][key] rows 128B, XOR-swizzled
  const int tid = threadIdx.x, lane = tid & 63, w = tid >> 6;
  const int hi = lane >> 5, lq = lane & 31;

  const int g = blockIdx.x;
  const int bh = (g & 7) * 4 + ((g >> 3) & 3);
  const int p  = g >> 5;                         // 0..7
  const int b = bh >> 4, h = bh & 15, kvh = h >> 1;

  const int tA = 15 - p;                         // long tile (warps 0-3)
  const int nk = 2 * tA + 2;
  const int wg = w >> 2, wl = w & 3;
  const int tq = (wg ? p : tA) * 128;
  const int qw = tq + wl * 32;
  const int qg = qw + lq;

  const bf16* Qg = Qh + (size_t)(b * 16 + h) * 2048 * 128;
  const bf16* Kg = Kh + (size_t)(b * 8 + kvh) * 2048 * 128;
  const bf16* Vg = Vt + (size_t)(b * 8 + kvh) * 128 * 2048;

  short8 qf[8];
#pragma unroll
  for (int dc = 0; dc < 8; dc++)
    qf[dc] = *(const short8*)(Qg + (size_t)qg * 128 + dc * 16 + hi * 8);

  f32x16 oacc[4] = {};
  float m = -1e30f, l = 0.f;

  auto stage = [&](int buf, int k0) {
#pragma unroll
    for (int i = 0; i < 2; i++) {
      int c = w * 2 + i;
      {
        int row = c * 4 + (lane >> 4);
        int cb = ((lane & 15) * 16) ^ ((row & 7) << 4);
        async_ld16((const char*)Kg + (size_t)(k0 + row) * 256 + cb,
                   (char*)Ks[buf] + c * 1024);
      }
      {
        int row = c * 8 + (lane >> 3);
        int cb = ((lane & 7) * 16) ^ ((row & 7) << 4);
        async_ld16((const char*)Vg + (size_t)row * 4096 + (size_t)k0 * 2 + cb,
                   (char*)Vs[buf] + c * 1024);
      }
    }
  };

  stage(0, 0);
  stage(1, 64);

  for (int s = 0; s < nk; ++s) {
    const int k0 = s * 64;
    if (s + 1 < nk) asm volatile("s_waitcnt vmcnt(4)" ::: "memory");
    else            asm volatile("s_waitcnt vmcnt(0)" ::: "memory");
    __builtin_amdgcn_s_barrier();

    if (k0 < qw + 32) {
      const int buf = s & 1;
      // ---- S^T = K . Q^T
      f32x16 st[2] = {};
#pragma unroll
      for (int kc = 0; kc < 2; kc++) {
        int row = kc * 32 + lq;
        int swz = (row & 7) << 4;
        const char* kbase = (const char*)Ks[buf] + row * 256;
#pragma unroll
        for (int dc = 0; dc < 8; dc++) {
          short8 kf = *(const short8*)(kbase + ((dc * 32 + hi * 16) ^ swz));
          st[kc] = __builtin_amdgcn_mfma_f32_32x32x16_bf16(kf, qf[dc], st[kc], 0, 0, 0);
        }
      }
      // ---- scale (log2 domain) + causal mask
      const float sc = 0.12751744416163417f;  // (1/sqrt(128)) * log2(e)
      const bool msk = (k0 + 63 > qw);
#pragma unroll
      for (int kc = 0; kc < 2; kc++)
#pragma unroll
        for (int rr = 0; rr < 16; rr++) {
          float v = st[kc][rr] * sc;
          if (msk) {
            int kg = k0 + kc * 32 + (rr & 3) + 8 * (rr >> 2) + 4 * hi;
            v = (kg <= qg) ? v : -1e30f;
          }
          st[kc][rr] = v;
        }
      // ---- row max: depth-5 tree + half exchange
      float mx[16];
#pragma unroll
      for (int rr = 0; rr < 16; rr++) mx[rr] = fmaxf(st[0][rr], st[1][rr]);
#pragma unroll
      for (int off = 8; off >= 1; off >>= 1)
#pragma unroll
        for (int rr = 0; rr < 8; rr++)
          if (rr < off) mx[rr] = fmaxf(mx[rr], mx[rr + off]);
      float pm = fmaxf(mx[0], __shfl_xor(mx[0], 32));
      // ---- defer-max rescale (THR=8 in log2 domain)
      if (__any(pm > m + 8.f)) {
        float mnew = fmaxf(m, pm);
        float alpha = exp2f(m - mnew);
        m = mnew;
        l *= alpha;
        float al[16];
#pragma unroll
        for (int rr = 0; rr < 16; rr++)
          al[rr] = __shfl(alpha, (rr & 3) + 8 * (rr >> 2) + 4 * hi);
#pragma unroll
        for (int dc = 0; dc < 4; dc++)
#pragma unroll
          for (int rr = 0; rr < 16; rr++) oacc[dc][rr] *= al[rr];
      }
      // ---- exp + row sum (tree)
#pragma unroll
      for (int kc = 0; kc < 2; kc++)
#pragma unroll
        for (int rr = 0; rr < 16; rr++) st[kc][rr] = exp2f(st[kc][rr] - m);
      float sm[16];
#pragma unroll
      for (int rr = 0; rr < 16; rr++) sm[rr] = st[0][rr] + st[1][rr];
#pragma unroll
      for (int off = 8; off >= 1; off >>= 1)
#pragma unroll
        for (int rr = 0; rr < 8; rr++)
          if (rr < off) sm[rr] += sm[rr + off];
      l += sm[0] + __shfl_xor(sm[0], 32);
      // ---- pack P into PV A-frags, exchange via lane^32
      short8 af[4];
#pragma unroll
      for (int kc = 0; kc < 2; kc++)
#pragma unroll
        for (int sb = 0; sb < 2; sb++) {
          int base = sb * 8;
          unsigned int a01 = cvt_pk_bf16(st[kc][base + 0], st[kc][base + 1]);
          unsigned int a23 = cvt_pk_bf16(st[kc][base + 2], st[kc][base + 3]);
          unsigned int b01 = cvt_pk_bf16(st[kc][base + 4], st[kc][base + 5]);
          unsigned int b23 = cvt_pk_bf16(st[kc][base + 6], st[kc][base + 7]);
          unsigned int xa01 = (unsigned int)__shfl_xor((int)a01, 32);
          unsigned int xa23 = (unsigned int)__shfl_xor((int)a23, 32);
          unsigned int xb01 = (unsigned int)__shfl_xor((int)b01, 32);
          unsigned int xb23 = (unsigned int)__shfl_xor((int)b23, 32);
          union { unsigned int u[4]; short8 s; } f;
          f.u[0] = hi ? xb01 : a01;
          f.u[1] = hi ? xb23 : a23;
          f.u[2] = hi ? b01 : xa01;
          f.u[3] = hi ? b23 : xa23;
          af[kc * 2 + sb] = f.s;
        }
      // ---- O += P . V
#pragma unroll
      for (int dc = 0; dc < 4; dc++) {
        int row = dc * 32 + lq;
        int swz = (row & 7) << 4;
        const char* vbase = (const char*)Vs[buf] + row * 128;
#pragma unroll
        for (int ks = 0; ks < 4; ks++) {
          short8 vf = *(const short8*)(vbase + ((ks * 32 + hi * 16) ^ swz));
          oacc[dc] = __builtin_amdgcn_mfma_f32_32x32x16_bf16(af[ks], vf, oacc[dc], 0, 0, 0);
        }
      }
    }

    __builtin_amdgcn_s_barrier();
    __builtin_amdgcn_sched_barrier(0);
    if (s + 2 < nk) stage(s & 1, (s + 2) * 64);
  }

  float inv = 1.f / l;
  float iv[16];
#pragma unroll
  for (int rr = 0; rr < 16; rr++)
    iv[rr] = __shfl(inv, (rr & 3) + 8 * (rr >> 2) + 4 * hi);
#pragma unroll
  for (int dc = 0; dc < 4; dc++)
#pragma unroll
    for (int rr = 0; rr < 16; rr++) {
      int t = qw + (rr & 3) + 8 * (rr >> 2) + 4 * hi;
      Y[(size_t)(b * 2048 + t) * 2048 + h * 128 + dc * 32 + lq] =
          __float2bfloat16(oacc[dc][rr] * iv[rr]);
    }
}

// ---------------------------------------------------------------- launcher
extern "C" void kernel_launch(void* const* d_in, const int* in_sizes, int n_in,
                              void* d_out, int out_size, void* d_ws, size_t ws_size,
                              hipStream_t stream) {
  (void)in_sizes; (void)n_in; (void)out_size; (void)ws_size;
  const float* x   = (const float*)d_in[0];
  const float* wq  = (const float*)d_in[1];
  const float* wk  = (const float*)d_in[2];
  const float* wv  = (const float*)d_in[3];
  const float* wo  = (const float*)d_in[4];
  const float* qnw = (const float*)d_in[5];
  const float* knw = (const float*)d_in[6];
  float* out = (float*)d_out;
  char* ws = (char*)d_ws;
  const size_t MB = 1u << 20;
  bf16*   xb  = (bf16*)(ws + 0 * MB);    // [4096][1024]
  bf16*   wt  = (bf16*)(ws + 8 * MB);    // [4096][1024]  rows: wq^T | wk^T | wv^T
  bf16*   wot = (bf16*)(ws + 16 * MB);   // [1024][2048]
  bf16*   qkv = (bf16*)(ws + 20 * MB);   // [4096][4096]
  float2* tab = (float2*)(ws + 52 * MB); // [2048][64]
  bf16*   Qh  = (bf16*)(ws + 53 * MB);   // [2][16][2048][128]
  bf16*   Kh  = (bf16*)(ws + 69 * MB);   // [2][8][2048][128]
  bf16*   Vtr = (bf16*)(ws + 77 * MB);   // [2][8][128][2048]  (V transposed)
  bf16*   Yb  = (bf16*)(ws + 85 * MB);   // [4096][2048]

  cvt_f32_bf16<<<4096, 256, 0, stream>>>(x, xb, 1048576);
  transpose_cvt3<<<dim3(32, 32, 4), 256, 0, stream>>>(wq, wk, wv, wt);
  transpose_cvt<<<dim3(32, 64), 256, 0, stream>>>(wo, wot, 2048, 1024);
  rope_tab<<<2048, 64, 0, stream>>>(tab);
  gemm256<<<dim3(16, 16), 512, 0, stream>>>(xb, wt, qkv, 4096, 4096, 1024);
  norm_rope<<<6144, 256, 0, stream>>>(qkv, qnw, knw, tab, Qh, Kh);
  v_transpose<<<dim3(64, 4, 16), 256, 0, stream>>>(qkv, Vtr);
  flash_attn7<<<256, 512, 0, stream>>>(Qh, Kh, Vtr, Yb);
  gemm_bt<true><<<dim3(8, 32), 256, 0, stream>>>(Yb, wot, out, 4096, 1024, 2048);
}